// Round 2
// baseline (1940.330 us; speedup 1.0000x reference)
//
#include <hip/hip_runtime.h>
#include <hip/hip_bf16.h>

#define DEV static __device__ __forceinline__

#define PIX 4096
#define SEQL 4096
#define BEPS 1e-5f

DEV float b2f(unsigned short u){ unsigned int i=((unsigned int)u)<<16; float f; __builtin_memcpy(&f,&i,4); return f; }
DEV unsigned short f2b(float f){ __hip_bfloat16 h=__float2bfloat16(f); unsigned short s; __builtin_memcpy(&s,&h,2); return s; }
DEV void unp2(unsigned int w, float&a, float&b){ unsigned int lo=w<<16, hi=w&0xffff0000u; __builtin_memcpy(&a,&lo,4); __builtin_memcpy(&b,&hi,4); }
DEV unsigned int pk2(float a,float b){ return (unsigned int)f2b(a)|((unsigned int)f2b(b)<<16); }
DEV float sigm(float x){ return 1.f/(1.f+__expf(-x)); }
DEV float silu_(float x){ return x*sigm(x); }
DEV float softplus_(float x){ return (x>20.f)?x:log1pf(__expf(x)); }

#define MACSTEP(ai, comp) \
  acc[0][0] += ai.x*w0.comp; acc[1][0] += ai.y*w0.comp; acc[2][0] += ai.z*w0.comp; acc[3][0] += ai.w*w0.comp; \
  acc[0][1] += ai.x*w1.comp; acc[1][1] += ai.y*w1.comp; acc[2][1] += ai.z*w1.comp; acc[3][1] += ai.w*w1.comp; \
  acc[0][2] += ai.x*w2.comp; acc[1][2] += ai.y*w2.comp; acc[2][2] += ai.z*w2.comp; acc[3][2] += ai.w*w2.comp; \
  acc[0][3] += ai.x*w3.comp; acc[1][3] += ai.y*w3.comp; acc[2][3] += ai.z*w3.comp; acc[3][3] += ai.w*w3.comp;

#define GEMM_COMPUTE() \
  _Pragma("unroll") \
  for (int kq=0;kq<8;++kq){ \
    float4 a0=*(const float4*)&sIn[kq*4+0][pq*4]; \
    float4 a1=*(const float4*)&sIn[kq*4+1][pq*4]; \
    float4 a2=*(const float4*)&sIn[kq*4+2][pq*4]; \
    float4 a3=*(const float4*)&sIn[kq*4+3][pq*4]; \
    float4 w0=*(const float4*)&sW[oq*4+0][kq*4]; \
    float4 w1=*(const float4*)&sW[oq*4+1][kq*4]; \
    float4 w2=*(const float4*)&sW[oq*4+2][kq*4]; \
    float4 w3=*(const float4*)&sW[oq*4+3][kq*4]; \
    MACSTEP(a0,x) MACSTEP(a1,y) MACSTEP(a2,z) MACSTEP(a3,w) \
  }

// ---------------- k1: conv1x1 256->512 + BN + ReLU ----------------
__global__ __launch_bounds__(256) void k1(const float* __restrict__ FT1,const float* __restrict__ FT2,
  const float* __restrict__ Wp,const float* __restrict__ gg,const float* __restrict__ gb,
  const float* __restrict__ gm,const float* __restrict__ gv,float* __restrict__ x1)
{
  __shared__ float sIn[32][68];
  __shared__ float sW[64][36];
  const int tid=threadIdx.x, pq=tid&15, oq=tid>>4;
  const int p0=blockIdx.x*64, oc0=blockIdx.y*64, b=blockIdx.z;
  float acc[4][4]={};
  for(int k0=0;k0<256;k0+=32){
    for(int l=tid;l<2048;l+=256){ int kk=l>>6, pp=l&63; int c=k0+kk;
      const float* s_=(c<128)? FT1+((size_t)b*128+c)*PIX : FT2+((size_t)b*128+c-128)*PIX;
      sIn[kk][pp]=s_[p0+pp]; }
    for(int l=tid;l<2048;l+=256){ int oc=l>>5, kk=l&31; sW[oc][kk]=Wp[(size_t)(oc0+oc)*256+k0+kk]; }
    __syncthreads();
    GEMM_COMPUTE();
    __syncthreads();
  }
  #pragma unroll
  for(int o=0;o<4;++o){ int oc=oc0+oq*4+o;
    float ks=gg[oc]*rsqrtf(gv[oc]+BEPS), kb=gb[oc]-gm[oc]*ks;
    float4 v; v.x=fmaxf(acc[0][o]*ks+kb,0.f); v.y=fmaxf(acc[1][o]*ks+kb,0.f);
    v.z=fmaxf(acc[2][o]*ks+kb,0.f); v.w=fmaxf(acc[3][o]*ks+kb,0.f);
    *(float4*)&x1[((size_t)b*512+oc)*PIX+p0+pq*4]=v; }
}

// ---------------- k2: depthwise 3x3 + BN + ReLU ----------------
__global__ __launch_bounds__(256) void k2(const float* __restrict__ x1,const float* __restrict__ cw,
  const float* __restrict__ gg,const float* __restrict__ gb,const float* __restrict__ gm,
  const float* __restrict__ gv,float* __restrict__ x2)
{
  int gid=blockIdx.x*256+threadIdx.x;
  int wq=gid&15, h=(gid>>4)&63, bc=gid>>10;
  int c=bc&511;
  const float* src=x1+(size_t)bc*PIX;
  float wv[9];
  #pragma unroll
  for(int i=0;i<9;++i) wv[i]=cw[c*9+i];
  float ks=gg[c]*rsqrtf(gv[c]+BEPS), kb=gb[c]-gm[c]*ks;
  int wb=wq*4;
  float o[4]={};
  #pragma unroll
  for(int dh=0;dh<3;++dh){ int hh=h+dh-1; if(hh<0||hh>63) continue;
    const float* row=src+hh*64;
    float rv[6];
    #pragma unroll
    for(int j=0;j<6;++j){ int wc=wb-1+j; rv[j]=(wc>=0&&wc<64)?row[wc]:0.f; }
    #pragma unroll
    for(int dw=0;dw<3;++dw){ float wgt=wv[dh*3+dw];
      #pragma unroll
      for(int i=0;i<4;++i) o[i]+=rv[i+dw]*wgt; } }
  float4 v; v.x=fmaxf(o[0]*ks+kb,0.f); v.y=fmaxf(o[1]*ks+kb,0.f);
  v.z=fmaxf(o[2]*ks+kb,0.f); v.w=fmaxf(o[3]*ks+kb,0.f);
  *(float4*)&x2[(size_t)bc*PIX+h*64+wb]=v;
}

// ---------------- k3: SE mean ----------------
__global__ __launch_bounds__(256) void k3(const float* __restrict__ x1,const float* __restrict__ x2,
  float* __restrict__ sr)
{
  int bc=blockIdx.x; int cg=bc&1023, b=bc>>10;
  const float* src=(cg<512)? x1+((size_t)b*512+cg)*PIX : x2+((size_t)b*512+cg-512)*PIX;
  float s=0;
  for(int i=threadIdx.x;i<1024;i+=256){ float4 v=((const float4*)src)[i]; s+=v.x+v.y+v.z+v.w; }
  #pragma unroll
  for(int off=32;off;off>>=1) s+=__shfl_down(s,off);
  __shared__ float red[4];
  if((threadIdx.x&63)==0) red[threadIdx.x>>6]=s;
  __syncthreads();
  if(threadIdx.x==0) sr[bc]=(red[0]+red[1]+red[2]+red[3])*(1.f/4096.f);
}

// ---------------- k4: SE MLP ----------------
__global__ __launch_bounds__(256) void k4(const float* __restrict__ sr,const float* __restrict__ w1,
  const float* __restrict__ w2,float* __restrict__ sOut)
{
  int b=blockIdx.x;
  __shared__ float ls[1024];
  __shared__ float pm[4][64];
  __shared__ float mid[64];
  for(int i=threadIdx.x;i<1024;i+=256) ls[i]=sr[b*1024+i];
  __syncthreads();
  int k=threadIdx.x&63, part=threadIdx.x>>6;
  float p=0;
  for(int c=part*256;c<part*256+256;++c) p+=ls[c]*w1[k*1024+c];
  pm[part][k]=p;
  __syncthreads();
  if(threadIdx.x<64) mid[threadIdx.x]=fmaxf(pm[0][threadIdx.x]+pm[1][threadIdx.x]+pm[2][threadIdx.x]+pm[3][threadIdx.x],0.f);
  __syncthreads();
  for(int j=threadIdx.x;j<1024;j+=256){
    float a=0;
    for(int kk=0;kk<64;++kk) a+=mid[kk]*w2[j*64+kk];
    sOut[b*1024+j]=sigm(a);
  }
}

// ---------------- k5: proj conv1x1 1024->128 (+SE scale) + BN3, writes Fp and FpT ----------------
__global__ __launch_bounds__(256) void k5(const float* __restrict__ x1,const float* __restrict__ x2,
  const float* __restrict__ sse,const float* __restrict__ Wp,
  const float* __restrict__ g3,const float* __restrict__ b3,const float* __restrict__ m3,
  const float* __restrict__ v3,float* __restrict__ Fp,float* __restrict__ FpT)
{
  __shared__ float sIn[32][68];
  __shared__ float sW[64][36];
  const int tid=threadIdx.x, pq=tid&15, oq=tid>>4;
  const int p0=blockIdx.x*64, oc0=blockIdx.y*64, b=blockIdx.z;
  float acc[4][4]={};
  for(int k0=0;k0<1024;k0+=32){
    for(int l=tid;l<2048;l+=256){ int kk=l>>6, pp=l&63; int c=k0+kk;
      const float* s_=(c<512)? x1+((size_t)b*512+c)*PIX : x2+((size_t)b*512+c-512)*PIX;
      sIn[kk][pp]=s_[p0+pp]*sse[b*1024+c]; }
    for(int l=tid;l<2048;l+=256){ int oc=l>>5, kk=l&31; sW[oc][kk]=Wp[(size_t)(oc0+oc)*1024+k0+kk]; }
    __syncthreads();
    GEMM_COMPUTE();
    __syncthreads();
  }
  #pragma unroll
  for(int o=0;o<4;++o){ int oc=oc0+oq*4+o;
    float ks=g3[oc]*rsqrtf(v3[oc]+BEPS), kb=b3[oc]-m3[oc]*ks;
    #pragma unroll
    for(int p=0;p<4;++p){ int pp=p0+pq*4+p; float val=acc[p][o]*ks+kb;
      Fp[((size_t)b*128+oc)*PIX+pp]=val;
      int q=((pp&63)<<6)|(pp>>6);
      FpT[((size_t)b*128+oc)*PIX+q]=val; } }
}

// ---------------- k6a: in_proj GEMM 128->512, writes xsT (raw) and zT (silu) in (n,c,t) bf16 ----------------
__global__ __launch_bounds__(256) void k6a(const float* __restrict__ Fp,const float* __restrict__ FpT,
  const float* __restrict__ Win,unsigned short* __restrict__ xsT,unsigned short* __restrict__ zT)
{
  __shared__ float sIn[32][68];
  __shared__ float sW[64][36];
  const int tid=threadIdx.x, pq=tid&15, oq=tid>>4;
  const int t0=blockIdx.x*64, r0=blockIdx.y*64, n=blockIdx.z;
  const int d=n>>3, b=n&7;
  const float* src=((d<2)?Fp:FpT)+(size_t)b*128*PIX;
  const int rev=(d&1)?63:0;
  float acc[4][4]={};
  for(int k0=0;k0<128;k0+=32){
    for(int l=tid;l<2048;l+=256){ int kk=l>>6, tt=l&63;
      int t=t0+tt; int tm=(t&~63)|((t&63)^rev);
      sIn[kk][tt]=src[(size_t)(k0+kk)*PIX+tm]; }
    for(int l=tid;l<2048;l+=256){ int r=l>>5, kk=l&31; sW[r][kk]=Win[(size_t)(r0+r)*128+k0+kk]; }
    __syncthreads();
    GEMM_COMPUTE();
    __syncthreads();
  }
  #pragma unroll
  for(int o=0;o<4;++o){ int r=r0+oq*4+o;
    float v0=acc[0][o],v1=acc[1][o],v2=acc[2][o],v3=acc[3][o];
    unsigned short* dst; int row;
    if(r<256){ dst=xsT; row=r; } else { dst=zT; row=r-256; v0=silu_(v0); v1=silu_(v1); v2=silu_(v2); v3=silu_(v3); }
    size_t base=((size_t)n*256+row)*SEQL+t0+pq*4;
    uint2 pk; pk.x=pk2(v0,v1); pk.y=pk2(v2,v3);
    *(uint2*)&dst[base]=pk; }
}

// ---------------- k6b: causal conv1d (k=4) + SiLU ----------------
__global__ __launch_bounds__(256) void k6b(const unsigned short* __restrict__ xsT,
  const float* __restrict__ cw,const float* __restrict__ cb,unsigned short* __restrict__ uT)
{
  int gid=blockIdx.x*256+threadIdx.x;
  int tb=gid&511, nc=gid>>9, c=nc&255;
  const unsigned short* row=xsT+(size_t)nc*SEQL;
  int t0=tb*8;
  float w0=cw[c*4+0],w1=cw[c*4+1],w2=cw[c*4+2],w3=cw[c*4+3],bb=cb[c];
  float xv[11];
  #pragma unroll
  for(int j=0;j<11;++j){ int t=t0-3+j; xv[j]=(t>=0)?b2f(row[t]):0.f; }
  unsigned int ow[4];
  #pragma unroll
  for(int i=0;i<8;i+=2){
    float a0=xv[i]*w0+xv[i+1]*w1+xv[i+2]*w2+xv[i+3]*w3+bb;
    float a1=xv[i+1]*w0+xv[i+2]*w1+xv[i+3]*w2+xv[i+4]*w3+bb;
    ow[i>>1]=pk2(silu_(a0),silu_(a1));
  }
  *(uint4*)&uT[(size_t)nc*SEQL+t0]=make_uint4(ow[0],ow[1],ow[2],ow[3]);
}

// ---------------- k6c: x_proj (10) + dt_proj + softplus -> dtT, Bc, Cc ----------------
__global__ __launch_bounds__(256) void k6c(const unsigned short* __restrict__ uT,
  const float* __restrict__ xpw,const float* __restrict__ dtw,const float* __restrict__ dtb,
  unsigned short* __restrict__ dtT,float* __restrict__ Bc,float* __restrict__ Cc)
{
  __shared__ unsigned short sU[64][64];
  __shared__ float sDbl[64][11];
  const int tid=threadIdx.x, tt=tid&63, kg=tid>>6;
  const int t0=blockIdx.x*64, n=blockIdx.y;
  const int ka=kg, kb_=kg+4, kc=kg+8;
  float a0=0,a1=0,a2=0;
  for(int cb=0;cb<4;++cb){
    for(int l=tid;l<4096;l+=256){ int cc=l>>6, t=l&63;
      sU[cc][t]=uT[((size_t)n*256+cb*64+cc)*SEQL+t0+t]; }
    __syncthreads();
    for(int cc=0;cc<64;++cc){
      float uv=b2f(sU[cc][tt]);
      int c=cb*64+cc;
      a0+=uv*xpw[ka*256+c];
      a1+=uv*xpw[kb_*256+c];
      if(kc<10) a2+=uv*xpw[kc*256+c];
    }
    __syncthreads();
  }
  sDbl[tt][ka]=a0; sDbl[tt][kb_]=a1; if(kg<2) sDbl[tt][kc]=a2;
  __syncthreads();
  if(kg==0) Bc[(size_t)n*SEQL+t0+tt]=sDbl[tt][8];
  else if(kg==1) Cc[(size_t)n*SEQL+t0+tt]=sDbl[tt][9];
  float d8[8];
  #pragma unroll
  for(int i=0;i<8;++i) d8[i]=sDbl[tt][i];
  for(int j=0;j<64;++j){
    int c=kg*64+j;
    float a=dtb[c];
    #pragma unroll
    for(int i=0;i<8;++i) a+=d8[i]*dtw[c*8+i];
    dtT[((size_t)n*256+c)*SEQL+t0+tt]=f2b(softplus_(a));
  }
}

// ---------------- k7: chunked scan (8 chunks of 512) ----------------
__global__ __launch_bounds__(256) void k7p1(const unsigned short* __restrict__ uT,
  const unsigned short* __restrict__ dtT,const float* __restrict__ Bc,
  const float* __restrict__ A_log,float* __restrict__ Pq)
{
  int g=blockIdx.x*256+threadIdx.x;
  int ch=g&7, nc=g>>3, c=nc&255, n=nc>>8;
  float A=-__expf(A_log[c]);
  size_t base=(size_t)nc*SEQL+ch*512;
  const float* bp=Bc+(size_t)n*SEQL+ch*512;
  float P=1.f,q=0.f;
  for(int t0=0;t0<512;t0+=8){
    uint4 uu=*(const uint4*)&uT[base+t0];
    uint4 dd=*(const uint4*)&dtT[base+t0];
    float uv[8],dv[8];
    unp2(uu.x,uv[0],uv[1]);unp2(uu.y,uv[2],uv[3]);unp2(uu.z,uv[4],uv[5]);unp2(uu.w,uv[6],uv[7]);
    unp2(dd.x,dv[0],dv[1]);unp2(dd.y,dv[2],dv[3]);unp2(dd.z,dv[4],dv[5]);unp2(dd.w,dv[6],dv[7]);
    #pragma unroll
    for(int i=0;i<8;++i){
      float e=__expf(dv[i]*A);
      q=q*e+dv[i]*bp[t0+i]*uv[i];
      P*=e;
    }
  }
  Pq[(size_t)g*2]=P; Pq[(size_t)g*2+1]=q;
}

__global__ __launch_bounds__(256) void k7mid(const float* __restrict__ Pq,float* __restrict__ h0)
{
  int nc=blockIdx.x*256+threadIdx.x;
  float h=0.f;
  #pragma unroll
  for(int k=0;k<8;++k){
    h0[(size_t)nc*8+k]=h;
    h=h*Pq[((size_t)nc*8+k)*2]+Pq[((size_t)nc*8+k)*2+1];
  }
}

__global__ __launch_bounds__(256) void k7p2(unsigned short* __restrict__ uT,
  const unsigned short* __restrict__ dtT,const unsigned short* __restrict__ zT,
  const float* __restrict__ Bc,const float* __restrict__ Cc,
  const float* __restrict__ A_log,const float* __restrict__ Dp,
  const float* __restrict__ h0)
{
  int g=blockIdx.x*256+threadIdx.x;
  int ch=g&7, nc=g>>3, c=nc&255, n=nc>>8;
  float A=-__expf(A_log[c]), Dv=Dp[c];
  size_t base=(size_t)nc*SEQL+ch*512;
  const float* bp=Bc+(size_t)n*SEQL+ch*512;
  const float* cp=Cc+(size_t)n*SEQL+ch*512;
  float h=h0[g];
  for(int t0=0;t0<512;t0+=8){
    uint4 uu=*(const uint4*)&uT[base+t0];
    uint4 dd=*(const uint4*)&dtT[base+t0];
    uint4 zz=*(const uint4*)&zT[base+t0];
    float uv[8],dv[8],zv[8],yv[8];
    unp2(uu.x,uv[0],uv[1]);unp2(uu.y,uv[2],uv[3]);unp2(uu.z,uv[4],uv[5]);unp2(uu.w,uv[6],uv[7]);
    unp2(dd.x,dv[0],dv[1]);unp2(dd.y,dv[2],dv[3]);unp2(dd.z,dv[4],dv[5]);unp2(dd.w,dv[6],dv[7]);
    unp2(zz.x,zv[0],zv[1]);unp2(zz.y,zv[2],zv[3]);unp2(zz.z,zv[4],zv[5]);unp2(zz.w,zv[6],zv[7]);
    #pragma unroll
    for(int i=0;i<8;++i){
      float e=__expf(dv[i]*A);
      h=h*e+dv[i]*bp[t0+i]*uv[i];
      yv[i]=(h*cp[t0+i]+uv[i]*Dv)*zv[i];
    }
    uint4 oo; oo.x=pk2(yv[0],yv[1]); oo.y=pk2(yv[2],yv[3]); oo.z=pk2(yv[4],yv[5]); oo.w=pk2(yv[6],yv[7]);
    *(uint4*)&uT[base+t0]=oo;
  }
}

// ---------------- k8a: out_proj GEMM 256->128 -> Y4 (n,t,oc) bf16 ----------------
__global__ __launch_bounds__(256) void k8a(const unsigned short* __restrict__ yT,
  const float* __restrict__ Wout,unsigned short* __restrict__ Y4)
{
  __shared__ float sIn[32][68];
  __shared__ float sW[64][36];
  const int tid=threadIdx.x, pq=tid&15, oq=tid>>4;
  const int t0=blockIdx.x*64, oc0=blockIdx.y*64, n=blockIdx.z;
  float acc[4][4]={};
  for(int k0=0;k0<256;k0+=32){
    for(int l=tid;l<2048;l+=256){ int kk=l>>6, tt=l&63;
      sIn[kk][tt]=b2f(yT[((size_t)n*256+k0+kk)*SEQL+t0+tt]); }
    for(int l=tid;l<2048;l+=256){ int oc=l>>5, kk=l&31; sW[oc][kk]=Wout[(size_t)(oc0+oc)*256+k0+kk]; }
    __syncthreads();
    GEMM_COMPUTE();
    __syncthreads();
  }
  #pragma unroll
  for(int p=0;p<4;++p){ int t=t0+pq*4+p;
    uint2 pk; pk.x=pk2(acc[p][0],acc[p][1]); pk.y=pk2(acc[p][2],acc[p][3]);
    *(uint2*)&Y4[((size_t)n*SEQL+t)*128+oc0+oq*4]=pk; }
}

// ---------------- k8b: pi GEMM + sigmoid gate + 4-dir sum ----------------
__global__ __launch_bounds__(256) void k8b(const float* __restrict__ Fp,const float* __restrict__ FpT,
  const unsigned short* __restrict__ Y4,const float* __restrict__ piw,const float* __restrict__ pib,
  float* __restrict__ ysum)
{
  __shared__ float sIn[32][68];
  __shared__ float sW[64][36];
  const int tid=threadIdx.x, pq=tid&15, oq=tid>>4;
  const int t0=blockIdx.x*64, oc0=blockIdx.y*64, b=blockIdx.z;
  float gs[4][4]={};
  for(int d=0;d<4;++d){
    int n=d*8+b;
    const float* src=((d<2)?Fp:FpT)+(size_t)b*128*PIX;
    const int rev=(d&1)?63:0;
    float acc[4][4]={};
    for(int k0=0;k0<256;k0+=32){
      if(k0<128){
        for(int l=tid;l<2048;l+=256){ int kk=l>>6, tt=l&63;
          int t=t0+tt; int tm=(t&~63)|((t&63)^rev);
          sIn[kk][tt]=src[(size_t)(k0+kk)*PIX+tm]; }
      } else {
        for(int l=tid;l<2048;l+=256){ int tt=l>>5, kk=l&31;
          sIn[kk][tt]=b2f(Y4[((size_t)n*SEQL+t0+tt)*128+(k0-128)+kk]); }
      }
      for(int l=tid;l<2048;l+=256){ int oc=l>>5, kk=l&31; sW[oc][kk]=piw[(size_t)(oc0+oc)*256+k0+kk]; }
      __syncthreads();
      GEMM_COMPUTE();
      __syncthreads();
    }
    #pragma unroll
    for(int o=0;o<4;++o){ int oc=oc0+oq*4+o;
      #pragma unroll
      for(int p=0;p<4;++p){ int t=t0+pq*4+p;
        float pi=sigm(acc[p][o]+pib[oc]);
        int tm=(t&~63)|((t&63)^rev);
        float x4=src[(size_t)oc*PIX+tm];
        float y4=b2f(Y4[((size_t)n*SEQL+t)*128+oc]);
        gs[p][o]+=y4*pi+x4*(1.f-pi); } }
  }
  #pragma unroll
  for(int p=0;p<4;++p){ int t=t0+pq*4+p;
    float4 v=make_float4(gs[p][0],gs[p][1],gs[p][2],gs[p][3]);
    *(float4*)&ysum[((size_t)b*SEQL+t)*128+oc0+oq*4]=v; }
}

// ---------------- k9: final conv1x1 (ysum + Fp) @ fw ----------------
__global__ __launch_bounds__(256) void k9(const float* __restrict__ ysum,const float* __restrict__ Fp,
  const float* __restrict__ fw,float* __restrict__ out)
{
  __shared__ float sIn[32][68];
  __shared__ float sW[64][36];
  const int tid=threadIdx.x, pq=tid&15, oq=tid>>4;
  const int p0=blockIdx.x*64, oc0=blockIdx.y*64, b=blockIdx.z;
  float acc[4][4]={};
  for(int k0=0;k0<128;k0+=32){
    for(int l=tid;l<2048;l+=256){ int pp=l>>5, kk=l&31;
      sIn[kk][pp]=ysum[((size_t)b*PIX+p0+pp)*128+k0+kk]; }
    for(int l=tid;l<2048;l+=256){ int oc=l>>5, kk=l&31; sW[oc][kk]=fw[(size_t)(oc0+oc)*128+k0+kk]; }
    __syncthreads();
    for(int l=tid;l<2048;l+=256){ int kk=l>>6, pp=l&63;
      sIn[kk][pp]+=Fp[((size_t)b*128+k0+kk)*PIX+p0+pp]; }
    __syncthreads();
    GEMM_COMPUTE();
    __syncthreads();
  }
  #pragma unroll
  for(int o=0;o<4;++o){ int oc=oc0+oq*4+o;
    float4 v=make_float4(acc[0][o],acc[1][o],acc[2][o],acc[3][o]);
    *(float4*)&out[((size_t)b*128+oc)*PIX+p0+pq*4]=v; }
}

extern "C" void kernel_launch(void* const* d_in,const int* in_sizes,int n_in,
  void* d_out,int out_size,void* d_ws,size_t ws_size,hipStream_t stream)
{
  (void)in_sizes; (void)n_in; (void)out_size; (void)ws_size;
  const float* FT1=(const float*)d_in[0];
  const float* FT2=(const float*)d_in[1];
  const float* gpw=(const float*)d_in[2];
  const float* g1g=(const float*)d_in[3];
  const float* g1b=(const float*)d_in[4];
  const float* g1m=(const float*)d_in[5];
  const float* g1v=(const float*)d_in[6];
  const float* gcw=(const float*)d_in[7];
  const float* g2g=(const float*)d_in[8];
  const float* g2b=(const float*)d_in[9];
  const float* g2m=(const float*)d_in[10];
  const float* g2v=(const float*)d_in[11];
  const float* sw1=(const float*)d_in[12];
  const float* sw2=(const float*)d_in[13];
  const float* prw=(const float*)d_in[14];
  const float* b3g=(const float*)d_in[15];
  const float* b3b=(const float*)d_in[16];
  const float* b3m=(const float*)d_in[17];
  const float* b3v=(const float*)d_in[18];
  const float* ipw=(const float*)d_in[19];
  const float* c1w=(const float*)d_in[20];
  const float* c1b=(const float*)d_in[21];
  const float* xpw=(const float*)d_in[22];
  const float* dtw=(const float*)d_in[23];
  const float* dtb=(const float*)d_in[24];
  const float* Alog=(const float*)d_in[25];
  const float* Dp=(const float*)d_in[26];
  const float* opw=(const float*)d_in[27];
  const float* piw=(const float*)d_in[28];
  const float* pib=(const float*)d_in[29];
  const float* fw=(const float*)d_in[30];

  char* w=(char*)d_ws;
  float* x1=(float*)(w);                                 // 64 MiB fp32
  float* x2=(float*)(w+(64ull<<20));                     // 64 MiB fp32
  unsigned short* uT=(unsigned short*)w;                 // aliases x1 (bf16, after k5)
  unsigned short* xsT=(unsigned short*)(w+(64ull<<20));  // aliases x2 (bf16, after k5)
  unsigned short* dtT=xsT;                               // aliases xsT (after k6b)
  unsigned short* Y4=xsT;                                // aliases dtT (after k7p2)
  unsigned short* zT=(unsigned short*)(w+(128ull<<20));  // 64 MiB bf16
  float* Fp=(float*)(w+(192ull<<20));                    // 16 MiB
  float* FpT=(float*)(w+(208ull<<20));                   // 16 MiB
  float* ysum=(float*)(w+(224ull<<20));                  // 16 MiB
  float* Bc=(float*)(w+(240ull<<20));                    // 512 KiB
  float* Cc=Bc+32*4096;                                  // 512 KiB
  float* sr=Cc+32*4096;                                  // 32 KiB
  float* sse=sr+8192;                                    // 32 KiB
  float* Pq=sse+8192;                                    // 512 KiB
  float* h0=Pq+131072;                                   // 256 KiB

  k1<<<dim3(64,8,8),256,0,stream>>>(FT1,FT2,gpw,g1g,g1b,g1m,g1v,x1);
  k2<<<16384,256,0,stream>>>(x1,gcw,g2g,g2b,g2m,g2v,x2);
  k3<<<8192,256,0,stream>>>(x1,x2,sr);
  k4<<<8,256,0,stream>>>(sr,sw1,sw2,sse);
  k5<<<dim3(64,2,8),256,0,stream>>>(x1,x2,sse,prw,b3g,b3b,b3m,b3v,Fp,FpT);
  k6a<<<dim3(64,8,32),256,0,stream>>>(Fp,FpT,ipw,xsT,zT);
  k6b<<<16384,256,0,stream>>>(xsT,c1w,c1b,uT);
  k6c<<<dim3(64,32),256,0,stream>>>(uT,xpw,dtw,dtb,dtT,Bc,Cc);
  k7p1<<<256,256,0,stream>>>(uT,dtT,Bc,Alog,Pq);
  k7mid<<<32,256,0,stream>>>(Pq,h0);
  k7p2<<<256,256,0,stream>>>(uT,dtT,zT,Bc,Cc,Alog,Dp,h0);
  k8a<<<dim3(64,2,32),256,0,stream>>>(uT,opw,Y4);
  k8b<<<dim3(64,2,8),256,0,stream>>>(Fp,FpT,Y4,piw,pib,ysum);
  k9<<<dim3(64,2,8),256,0,stream>>>(ysum,Fp,fw,(float*)d_out);
}

// Round 3
// 1184.114 us; speedup vs baseline: 1.6386x; 1.6386x over previous
//
#include <hip/hip_runtime.h>
#include <hip/hip_bf16.h>

#define DEV static __device__ __forceinline__

#define PIX 4096
#define SEQL 4096
#define BEPS 1e-5f

DEV float b2f(unsigned short u){ unsigned int i=((unsigned int)u)<<16; float f; __builtin_memcpy(&f,&i,4); return f; }
DEV unsigned short f2b(float f){ __hip_bfloat16 h=__float2bfloat16(f); unsigned short s; __builtin_memcpy(&s,&h,2); return s; }
DEV short f2bs(float f){ return (short)f2b(f); }
DEV void unp2(unsigned int w, float&a, float&b){ unsigned int lo=w<<16, hi=w&0xffff0000u; __builtin_memcpy(&a,&lo,4); __builtin_memcpy(&b,&hi,4); }
DEV unsigned int pk2(float a,float b){ return (unsigned int)f2b(a)|((unsigned int)f2b(b)<<16); }
DEV float sigm(float x){ return 1.f/(1.f+__expf(-x)); }
DEV float silu_(float x){ return x*sigm(x); }
DEV float softplus_(float x){ return (x>20.f)?x:log1pf(__expf(x)); }

using short8 = __attribute__((ext_vector_type(8))) short;
using f32x4  = __attribute__((ext_vector_type(4))) float;
#define MFMA16 __builtin_amdgcn_mfma_f32_16x16x32_bf16

// ================= MFMA GEMM skeleton =================
// tile 64(M) x 64(N) x 64(K), 256 threads = 4 waves (2x2), 2x2 16x16 frags/wave.
// sA: [k][m] with chunk-XOR swizzle (per-element frag reads)
// sW: [n][k] with chunk-XOR swizzle (ds_read_b128 frag reads, 144B row stride = 16B aligned)

#define MF_PRE() \
  const int tid=threadIdx.x; \
  const int lane=tid&63, wid=tid>>6; \
  const int wm=wid&1, wn=wid>>1; \
  const int fr=lane&15, fg=lane>>4; \
  const int srow=tid>>2, sch=tid&3;

#define STAGE_A(EXPRF) { \
  union { short h[16]; uint4 q[2]; } tmpa; \
  _Pragma("unroll") \
  for(int j=0;j<16;++j){ float v_=(EXPRF); tmpa.h[j]=f2bs(v_); } \
  int sw_=((sch^(srow&3))*16); \
  *(uint4*)&sA[srow*72+sw_]=tmpa.q[0]; \
  *(uint4*)&sA[srow*72+sw_+8]=tmpa.q[1]; }

#define STAGE_A_BF(PTR) { \
  const unsigned short* ap_=(PTR); \
  uint4 q0_=*(const uint4*)ap_, q1_=*(const uint4*)(ap_+8); \
  int sw_=((sch^(srow&3))*16); \
  *(uint4*)&sA[srow*72+sw_]=q0_; \
  *(uint4*)&sA[srow*72+sw_+8]=q1_; }

#define STAGE_W(PTR,LDK) { \
  const float* wp_=(PTR)+(size_t)(n0+srow)*(LDK)+k0+sch*16; \
  union { short h[16]; uint4 q[2]; } tmpw; \
  _Pragma("unroll") \
  for(int j=0;j<16;++j) tmpw.h[j]=f2bs(wp_[j]); \
  int sw_=((sch^(srow&3))*16); \
  *(uint4*)&sW[srow*72+sw_]=tmpw.q[0]; \
  *(uint4*)&sW[srow*72+sw_+8]=tmpw.q[1]; }

#define MF_STEP() \
  _Pragma("unroll") \
  for(int kk=0;kk<64;kk+=32){ \
    short8 af[2],bfv[2]; \
    _Pragma("unroll") \
    for(int i=0;i<2;++i){ int ml=wm*32+i*16+fr; \
      _Pragma("unroll") \
      for(int j8=0;j8<8;++j8){ int k_=kk+fg*8+j8; \
        af[i][j8]=sA[k_*72+(((ml>>4)^(k_&3))*16)+(ml&15)]; } } \
    _Pragma("unroll") \
    for(int jn=0;jn<2;++jn){ int nl=wn*32+jn*16+fr; int kb_=kk+fg*8; \
      bfv[jn]=*(const short8*)&sW[nl*72+(((kb_>>4)^(nl&3))*16)+(kb_&15)]; } \
    _Pragma("unroll") \
    for(int i=0;i<2;++i) \
      _Pragma("unroll") \
      for(int jn=0;jn<2;++jn) acc[i][jn]=MFMA16(af[i],bfv[jn],acc[i][jn],0,0,0); }

// ---------------- k1m: conv1x1 256->512 + BN + ReLU (MFMA) ----------------
__global__ __launch_bounds__(256) void k1m(const float* __restrict__ FT1,const float* __restrict__ FT2,
  const float* __restrict__ Wp,const float* __restrict__ gg,const float* __restrict__ gb,
  const float* __restrict__ gm,const float* __restrict__ gv,float* __restrict__ x1)
{
  MF_PRE();
  __shared__ __align__(16) short sA[64*72];
  __shared__ __align__(16) short sW[64*72];
  const int m0=blockIdx.x*64, n0=blockIdx.y*64, b=blockIdx.z;
  f32x4 acc[2][2]={};
  for(int k0=0;k0<256;k0+=64){
    { int c=k0+srow;
      const float* s_=(c<128)? FT1+((size_t)b*128+c)*PIX : FT2+((size_t)b*128+c-128)*PIX;
      const float* ap=s_+m0+sch*16;
      STAGE_A(ap[j]); }
    STAGE_W(Wp,256);
    __syncthreads();
    MF_STEP();
    __syncthreads();
  }
  #pragma unroll
  for(int jn=0;jn<2;++jn){ int oc=n0+wn*32+jn*16+fr;
    float ks=gg[oc]*rsqrtf(gv[oc]+BEPS), kb=gb[oc]-gm[oc]*ks;
    #pragma unroll
    for(int i=0;i<2;++i){ int mb=m0+wm*32+i*16+fg*4;
      float4 v; v.x=fmaxf(acc[i][jn][0]*ks+kb,0.f); v.y=fmaxf(acc[i][jn][1]*ks+kb,0.f);
      v.z=fmaxf(acc[i][jn][2]*ks+kb,0.f); v.w=fmaxf(acc[i][jn][3]*ks+kb,0.f);
      *(float4*)&x1[((size_t)b*512+oc)*PIX+mb]=v; } }
}

// ---------------- k2: depthwise 3x3 + BN + ReLU ----------------
__global__ __launch_bounds__(256) void k2(const float* __restrict__ x1,const float* __restrict__ cw,
  const float* __restrict__ gg,const float* __restrict__ gb,const float* __restrict__ gm,
  const float* __restrict__ gv,float* __restrict__ x2)
{
  int gid=blockIdx.x*256+threadIdx.x;
  int wq=gid&15, h=(gid>>4)&63, bc=gid>>10;
  int c=bc&511;
  const float* src=x1+(size_t)bc*PIX;
  float wv[9];
  #pragma unroll
  for(int i=0;i<9;++i) wv[i]=cw[c*9+i];
  float ks=gg[c]*rsqrtf(gv[c]+BEPS), kb=gb[c]-gm[c]*ks;
  int wb=wq*4;
  float o[4]={};
  #pragma unroll
  for(int dh=0;dh<3;++dh){ int hh=h+dh-1; if(hh<0||hh>63) continue;
    const float* row=src+hh*64;
    float rv[6];
    #pragma unroll
    for(int j=0;j<6;++j){ int wc=wb-1+j; rv[j]=(wc>=0&&wc<64)?row[wc]:0.f; }
    #pragma unroll
    for(int dw=0;dw<3;++dw){ float wgt=wv[dh*3+dw];
      #pragma unroll
      for(int i=0;i<4;++i) o[i]+=rv[i+dw]*wgt; } }
  float4 v; v.x=fmaxf(o[0]*ks+kb,0.f); v.y=fmaxf(o[1]*ks+kb,0.f);
  v.z=fmaxf(o[2]*ks+kb,0.f); v.w=fmaxf(o[3]*ks+kb,0.f);
  *(float4*)&x2[(size_t)bc*PIX+h*64+wb]=v;
}

// ---------------- k3: SE mean ----------------
__global__ __launch_bounds__(256) void k3(const float* __restrict__ x1,const float* __restrict__ x2,
  float* __restrict__ sr)
{
  int bc=blockIdx.x; int cg=bc&1023, b=bc>>10;
  const float* src=(cg<512)? x1+((size_t)b*512+cg)*PIX : x2+((size_t)b*512+cg-512)*PIX;
  float s=0;
  for(int i=threadIdx.x;i<1024;i+=256){ float4 v=((const float4*)src)[i]; s+=v.x+v.y+v.z+v.w; }
  #pragma unroll
  for(int off=32;off;off>>=1) s+=__shfl_down(s,off);
  __shared__ float red[4];
  if((threadIdx.x&63)==0) red[threadIdx.x>>6]=s;
  __syncthreads();
  if(threadIdx.x==0) sr[bc]=(red[0]+red[1]+red[2]+red[3])*(1.f/4096.f);
}

// ---------------- k4: SE MLP ----------------
__global__ __launch_bounds__(256) void k4(const float* __restrict__ sr,const float* __restrict__ w1,
  const float* __restrict__ w2,float* __restrict__ sOut)
{
  int b=blockIdx.x;
  __shared__ float ls[1024];
  __shared__ float pm[4][64];
  __shared__ float mid[64];
  for(int i=threadIdx.x;i<1024;i+=256) ls[i]=sr[b*1024+i];
  __syncthreads();
  int k=threadIdx.x&63, part=threadIdx.x>>6;
  float p=0;
  for(int c=part*256;c<part*256+256;++c) p+=ls[c]*w1[k*1024+c];
  pm[part][k]=p;
  __syncthreads();
  if(threadIdx.x<64) mid[threadIdx.x]=fmaxf(pm[0][threadIdx.x]+pm[1][threadIdx.x]+pm[2][threadIdx.x]+pm[3][threadIdx.x],0.f);
  __syncthreads();
  for(int j=threadIdx.x;j<1024;j+=256){
    float a=0;
    for(int kk=0;kk<64;++kk) a+=mid[kk]*w2[j*64+kk];
    sOut[b*1024+j]=sigm(a);
  }
}

// ---------------- k5m: proj 1024->128 (+SE) + BN3 -> Fp, FpT (MFMA) ----------------
__global__ __launch_bounds__(256) void k5m(const float* __restrict__ x1,const float* __restrict__ x2,
  const float* __restrict__ sse,const float* __restrict__ Wp,
  const float* __restrict__ g3,const float* __restrict__ b3,const float* __restrict__ m3,
  const float* __restrict__ v3,float* __restrict__ Fp,float* __restrict__ FpT)
{
  MF_PRE();
  __shared__ __align__(16) short sA[64*72];
  __shared__ __align__(16) short sW[64*72];
  const int m0=blockIdx.x*64, n0=blockIdx.y*64, b=blockIdx.z;
  f32x4 acc[2][2]={};
  for(int k0=0;k0<1024;k0+=64){
    { int c=k0+srow;
      const float* s_=(c<512)? x1+((size_t)b*512+c)*PIX : x2+((size_t)b*512+c-512)*PIX;
      float sc=sse[b*1024+c];
      const float* ap=s_+m0+sch*16;
      STAGE_A(ap[j]*sc); }
    STAGE_W(Wp,1024);
    __syncthreads();
    MF_STEP();
    __syncthreads();
  }
  #pragma unroll
  for(int jn=0;jn<2;++jn){ int oc=n0+wn*32+jn*16+fr;
    float ks=g3[oc]*rsqrtf(v3[oc]+BEPS), kb=b3[oc]-m3[oc]*ks;
    #pragma unroll
    for(int i=0;i<2;++i){ int mb=m0+wm*32+i*16+fg*4;
      float vv[4];
      #pragma unroll
      for(int p=0;p<4;++p) vv[p]=acc[i][jn][p]*ks+kb;
      *(float4*)&Fp[((size_t)b*128+oc)*PIX+mb]=make_float4(vv[0],vv[1],vv[2],vv[3]);
      #pragma unroll
      for(int p=0;p<4;++p){ int pp=mb+p; int q=((pp&63)<<6)|(pp>>6);
        FpT[((size_t)b*128+oc)*PIX+q]=vv[p]; } } }
}

// ---------------- k6am: in_proj 128->512 -> xsT, zT (MFMA) ----------------
__global__ __launch_bounds__(256) void k6am(const float* __restrict__ Fp,const float* __restrict__ FpT,
  const float* __restrict__ Win,unsigned short* __restrict__ xsT,unsigned short* __restrict__ zT)
{
  MF_PRE();
  __shared__ __align__(16) short sA[64*72];
  __shared__ __align__(16) short sW[64*72];
  const int m0=blockIdx.x*64, n0=blockIdx.y*64, n=blockIdx.z;
  const int d=n>>3, b=n&7;
  const float* src=((d<2)?Fp:FpT)+(size_t)b*128*PIX;
  const int rev=(d&1)?63:0;
  f32x4 acc[2][2]={};
  for(int k0=0;k0<128;k0+=64){
    { const float* ap=src+(size_t)(k0+srow)*PIX+m0;
      STAGE_A(ap[(sch*16+j)^rev]); }
    STAGE_W(Win,128);
    __syncthreads();
    MF_STEP();
    __syncthreads();
  }
  #pragma unroll
  for(int jn=0;jn<2;++jn){ int r=n0+wn*32+jn*16+fr;
    unsigned short* dst; int row; bool dosilu;
    if(r<256){ dst=xsT; row=r; dosilu=false; } else { dst=zT; row=r-256; dosilu=true; }
    #pragma unroll
    for(int i=0;i<2;++i){ int mb=m0+wm*32+i*16+fg*4;
      float v0=acc[i][jn][0],v1=acc[i][jn][1],v2=acc[i][jn][2],v3=acc[i][jn][3];
      if(dosilu){ v0=silu_(v0); v1=silu_(v1); v2=silu_(v2); v3=silu_(v3); }
      uint2 pk; pk.x=pk2(v0,v1); pk.y=pk2(v2,v3);
      *(uint2*)&dst[((size_t)n*256+row)*SEQL+mb]=pk; } }
}

// ---------------- k6b: causal conv1d (k=4) + SiLU ----------------
__global__ __launch_bounds__(256) void k6b(const unsigned short* __restrict__ xsT,
  const float* __restrict__ cw,const float* __restrict__ cb,unsigned short* __restrict__ uT)
{
  int gid=blockIdx.x*256+threadIdx.x;
  int tb=gid&511, nc=gid>>9, c=nc&255;
  const unsigned short* row=xsT+(size_t)nc*SEQL;
  int t0=tb*8;
  float w0=cw[c*4+0],w1=cw[c*4+1],w2=cw[c*4+2],w3=cw[c*4+3],bb=cb[c];
  float xv[11];
  #pragma unroll
  for(int j=0;j<11;++j){ int t=t0-3+j; xv[j]=(t>=0)?b2f(row[t]):0.f; }
  unsigned int ow[4];
  #pragma unroll
  for(int i=0;i<8;i+=2){
    float a0=xv[i]*w0+xv[i+1]*w1+xv[i+2]*w2+xv[i+3]*w3+bb;
    float a1=xv[i+1]*w0+xv[i+2]*w1+xv[i+3]*w2+xv[i+4]*w3+bb;
    ow[i>>1]=pk2(silu_(a0),silu_(a1));
  }
  *(uint4*)&uT[(size_t)nc*SEQL+t0]=make_uint4(ow[0],ow[1],ow[2],ow[3]);
}

// ---------------- k6c: x_proj (10) + dt_proj + softplus -> dtT, Bc, Cc ----------------
__global__ __launch_bounds__(256) void k6c(const unsigned short* __restrict__ uT,
  const float* __restrict__ xpw,const float* __restrict__ dtw,const float* __restrict__ dtb,
  unsigned short* __restrict__ dtT,float* __restrict__ Bc,float* __restrict__ Cc)
{
  __shared__ unsigned short sU[64][64];
  __shared__ float sDbl[64][11];
  const int tid=threadIdx.x, tt=tid&63, kg=tid>>6;
  const int t0=blockIdx.x*64, n=blockIdx.y;
  const int ka=kg, kb_=kg+4, kc=kg+8;
  float a0=0,a1=0,a2=0;
  for(int cb=0;cb<4;++cb){
    for(int l=tid;l<4096;l+=256){ int cc=l>>6, t=l&63;
      sU[cc][t]=uT[((size_t)n*256+cb*64+cc)*SEQL+t0+t]; }
    __syncthreads();
    for(int cc=0;cc<64;++cc){
      float uv=b2f(sU[cc][tt]);
      int c=cb*64+cc;
      a0+=uv*xpw[ka*256+c];
      a1+=uv*xpw[kb_*256+c];
      if(kc<10) a2+=uv*xpw[kc*256+c];
    }
    __syncthreads();
  }
  sDbl[tt][ka]=a0; sDbl[tt][kb_]=a1; if(kg<2) sDbl[tt][kc]=a2;
  __syncthreads();
  if(kg==0) Bc[(size_t)n*SEQL+t0+tt]=sDbl[tt][8];
  else if(kg==1) Cc[(size_t)n*SEQL+t0+tt]=sDbl[tt][9];
  float d8[8];
  #pragma unroll
  for(int i=0;i<8;++i) d8[i]=sDbl[tt][i];
  for(int j=0;j<64;++j){
    int c=kg*64+j;
    float a=dtb[c];
    #pragma unroll
    for(int i=0;i<8;++i) a+=d8[i]*dtw[c*8+i];
    dtT[((size_t)n*256+c)*SEQL+t0+tt]=f2b(softplus_(a));
  }
}

// ---------------- k7: chunked scan (8 chunks of 512) ----------------
__global__ __launch_bounds__(256) void k7p1(const unsigned short* __restrict__ uT,
  const unsigned short* __restrict__ dtT,const float* __restrict__ Bc,
  const float* __restrict__ A_log,float* __restrict__ Pq)
{
  int g=blockIdx.x*256+threadIdx.x;
  int ch=g&7, nc=g>>3, c=nc&255, n=nc>>8;
  float A=-__expf(A_log[c]);
  size_t base=(size_t)nc*SEQL+ch*512;
  const float* bp=Bc+(size_t)n*SEQL+ch*512;
  float P=1.f,q=0.f;
  for(int t0=0;t0<512;t0+=8){
    uint4 uu=*(const uint4*)&uT[base+t0];
    uint4 dd=*(const uint4*)&dtT[base+t0];
    float uv[8],dv[8];
    unp2(uu.x,uv[0],uv[1]);unp2(uu.y,uv[2],uv[3]);unp2(uu.z,uv[4],uv[5]);unp2(uu.w,uv[6],uv[7]);
    unp2(dd.x,dv[0],dv[1]);unp2(dd.y,dv[2],dv[3]);unp2(dd.z,dv[4],dv[5]);unp2(dd.w,dv[6],dv[7]);
    #pragma unroll
    for(int i=0;i<8;++i){
      float e=__expf(dv[i]*A);
      q=q*e+dv[i]*bp[t0+i]*uv[i];
      P*=e;
    }
  }
  Pq[(size_t)g*2]=P; Pq[(size_t)g*2+1]=q;
}

__global__ __launch_bounds__(256) void k7mid(const float* __restrict__ Pq,float* __restrict__ h0)
{
  int nc=blockIdx.x*256+threadIdx.x;
  float h=0.f;
  #pragma unroll
  for(int k=0;k<8;++k){
    h0[(size_t)nc*8+k]=h;
    h=h*Pq[((size_t)nc*8+k)*2]+Pq[((size_t)nc*8+k)*2+1];
  }
}

__global__ __launch_bounds__(256) void k7p2(unsigned short* __restrict__ uT,
  const unsigned short* __restrict__ dtT,const unsigned short* __restrict__ zT,
  const float* __restrict__ Bc,const float* __restrict__ Cc,
  const float* __restrict__ A_log,const float* __restrict__ Dp,
  const float* __restrict__ h0)
{
  int g=blockIdx.x*256+threadIdx.x;
  int ch=g&7, nc=g>>3, c=nc&255, n=nc>>8;
  float A=-__expf(A_log[c]), Dv=Dp[c];
  size_t base=(size_t)nc*SEQL+ch*512;
  const float* bp=Bc+(size_t)n*SEQL+ch*512;
  const float* cp=Cc+(size_t)n*SEQL+ch*512;
  float h=h0[g];
  for(int t0=0;t0<512;t0+=8){
    uint4 uu=*(const uint4*)&uT[base+t0];
    uint4 dd=*(const uint4*)&dtT[base+t0];
    uint4 zz=*(const uint4*)&zT[base+t0];
    float uv[8],dv[8],zv[8],yv[8];
    unp2(uu.x,uv[0],uv[1]);unp2(uu.y,uv[2],uv[3]);unp2(uu.z,uv[4],uv[5]);unp2(uu.w,uv[6],uv[7]);
    unp2(dd.x,dv[0],dv[1]);unp2(dd.y,dv[2],dv[3]);unp2(dd.z,dv[4],dv[5]);unp2(dd.w,dv[6],dv[7]);
    unp2(zz.x,zv[0],zv[1]);unp2(zz.y,zv[2],zv[3]);unp2(zz.z,zv[4],zv[5]);unp2(zz.w,zv[6],zv[7]);
    #pragma unroll
    for(int i=0;i<8;++i){
      float e=__expf(dv[i]*A);
      h=h*e+dv[i]*bp[t0+i]*uv[i];
      yv[i]=(h*cp[t0+i]+uv[i]*Dv)*zv[i];
    }
    uint4 oo; oo.x=pk2(yv[0],yv[1]); oo.y=pk2(yv[2],yv[3]); oo.z=pk2(yv[4],yv[5]); oo.w=pk2(yv[6],yv[7]);
    *(uint4*)&uT[base+t0]=oo;
  }
}

// ---------------- k8am: out_proj 256->128 -> Y4 [n][oc][t] bf16 (MFMA) ----------------
__global__ __launch_bounds__(256) void k8am(const unsigned short* __restrict__ yT,
  const float* __restrict__ Wout,unsigned short* __restrict__ Y4)
{
  MF_PRE();
  __shared__ __align__(16) short sA[64*72];
  __shared__ __align__(16) short sW[64*72];
  const int m0=blockIdx.x*64, n0=blockIdx.y*64, n=blockIdx.z;
  const unsigned short* ybase=yT+(size_t)n*256*SEQL;
  f32x4 acc[2][2]={};
  for(int k0=0;k0<256;k0+=64){
    STAGE_A_BF(ybase+(size_t)(k0+srow)*SEQL+m0+sch*16);
    STAGE_W(Wout,256);
    __syncthreads();
    MF_STEP();
    __syncthreads();
  }
  #pragma unroll
  for(int jn=0;jn<2;++jn){ int oc=n0+wn*32+jn*16+fr;
    #pragma unroll
    for(int i=0;i<2;++i){ int mb=m0+wm*32+i*16+fg*4;
      uint2 pk; pk.x=pk2(acc[i][jn][0],acc[i][jn][1]); pk.y=pk2(acc[i][jn][2],acc[i][jn][3]);
      *(uint2*)&Y4[((size_t)n*128+oc)*SEQL+mb]=pk; } }
}

// ---------------- k8bm: pi GEMM + sigmoid gate + 4-dir sum -> ysum [b][c][t] (MFMA) ----------------
__global__ __launch_bounds__(256) void k8bm(const float* __restrict__ Fp,const float* __restrict__ FpT,
  const unsigned short* __restrict__ Y4,const float* __restrict__ piw,const float* __restrict__ pib,
  float* __restrict__ ysum)
{
  MF_PRE();
  __shared__ __align__(16) short sA[64*72];
  __shared__ __align__(16) short sW[64*72];
  const int m0=blockIdx.x*64, n0=blockIdx.y*64, b=blockIdx.z;
  f32x4 gs[2][2]={};
  for(int d=0;d<4;++d){
    const int n=d*8+b;
    const float* src=((d<2)?Fp:FpT)+(size_t)b*128*PIX;
    const int rev=(d&1)?63:0;
    f32x4 acc[2][2]={};
    for(int k0=0;k0<256;k0+=64){
      { int c=k0+srow;
        if(c<128){
          const float* ap=src+(size_t)c*PIX+m0;
          STAGE_A(ap[(sch*16+j)^rev]);
        } else {
          STAGE_A_BF(Y4+((size_t)n*128+(c-128))*SEQL+m0+sch*16);
        } }
      STAGE_W(piw,256);
      __syncthreads();
      MF_STEP();
      __syncthreads();
    }
    #pragma unroll
    for(int i=0;i<2;++i){
      #pragma unroll
      for(int jn=0;jn<2;++jn){
        int oc=n0+wn*32+jn*16+fr;
        int mb=m0+wm*32+i*16+fg*4;
        float pb=pib[oc];
        const float* xrow=src+(size_t)oc*PIX;
        const unsigned short* yrow=Y4+((size_t)n*128+oc)*SEQL;
        #pragma unroll
        for(int p=0;p<4;++p){
          int t=mb+p; int tm=(t&~63)|((t&63)^rev);
          float pi=sigm(acc[i][jn][p]+pb);
          float x4=xrow[tm];
          float y4=b2f(yrow[t]);
          gs[i][jn][p]+=y4*pi+x4*(1.f-pi);
        }
      }
    }
  }
  #pragma unroll
  for(int i=0;i<2;++i)
    #pragma unroll
    for(int jn=0;jn<2;++jn){
      int oc=n0+wn*32+jn*16+fr;
      int mb=m0+wm*32+i*16+fg*4;
      *(float4*)&ysum[((size_t)b*128+oc)*PIX+mb]=make_float4(gs[i][jn][0],gs[i][jn][1],gs[i][jn][2],gs[i][jn][3]);
    }
}

// ---------------- k9: final conv1x1 (ysum + Fp) @ fw  (fp32 SIMT) ----------------
#define MACSTEP(ai, comp) \
  acc[0][0] += ai.x*w0.comp; acc[1][0] += ai.y*w0.comp; acc[2][0] += ai.z*w0.comp; acc[3][0] += ai.w*w0.comp; \
  acc[0][1] += ai.x*w1.comp; acc[1][1] += ai.y*w1.comp; acc[2][1] += ai.z*w1.comp; acc[3][1] += ai.w*w1.comp; \
  acc[0][2] += ai.x*w2.comp; acc[1][2] += ai.y*w2.comp; acc[2][2] += ai.z*w2.comp; acc[3][2] += ai.w*w2.comp; \
  acc[0][3] += ai.x*w3.comp; acc[1][3] += ai.y*w3.comp; acc[2][3] += ai.z*w3.comp; acc[3][3] += ai.w*w3.comp;

#define GEMM_COMPUTE() \
  _Pragma("unroll") \
  for (int kq=0;kq<8;++kq){ \
    float4 a0=*(const float4*)&sIn[kq*4+0][pq*4]; \
    float4 a1=*(const float4*)&sIn[kq*4+1][pq*4]; \
    float4 a2=*(const float4*)&sIn[kq*4+2][pq*4]; \
    float4 a3=*(const float4*)&sIn[kq*4+3][pq*4]; \
    float4 w0=*(const float4*)&sWf[oq*4+0][kq*4]; \
    float4 w1=*(const float4*)&sWf[oq*4+1][kq*4]; \
    float4 w2=*(const float4*)&sWf[oq*4+2][kq*4]; \
    float4 w3=*(const float4*)&sWf[oq*4+3][kq*4]; \
    MACSTEP(a0,x) MACSTEP(a1,y) MACSTEP(a2,z) MACSTEP(a3,w) \
  }

__global__ __launch_bounds__(256) void k9(const float* __restrict__ ysum,const float* __restrict__ Fp,
  const float* __restrict__ fw,float* __restrict__ out)
{
  __shared__ float sIn[32][68];
  __shared__ float sWf[64][36];
  const int tid=threadIdx.x, pq=tid&15, oq=tid>>4;
  const int p0=blockIdx.x*64, oc0=blockIdx.y*64, b=blockIdx.z;
  float acc[4][4]={};
  for(int k0=0;k0<128;k0+=32){
    for(int l=tid;l<2048;l+=256){ int kk=l>>6, pp=l&63;
      size_t off=((size_t)b*128+k0+kk)*PIX+p0+pp;
      sIn[kk][pp]=ysum[off]+Fp[off]; }
    for(int l=tid;l<2048;l+=256){ int oc=l>>5, kk=l&31; sWf[oc][kk]=fw[(size_t)(oc0+oc)*128+k0+kk]; }
    __syncthreads();
    GEMM_COMPUTE();
    __syncthreads();
  }
  #pragma unroll
  for(int o=0;o<4;++o){ int oc=oc0+oq*4+o;
    float4 v=make_float4(acc[0][o],acc[1][o],acc[2][o],acc[3][o]);
    *(float4*)&out[((size_t)b*128+oc)*PIX+p0+pq*4]=v; }
}

extern "C" void kernel_launch(void* const* d_in,const int* in_sizes,int n_in,
  void* d_out,int out_size,void* d_ws,size_t ws_size,hipStream_t stream)
{
  (void)in_sizes; (void)n_in; (void)out_size; (void)ws_size;
  const float* FT1=(const float*)d_in[0];
  const float* FT2=(const float*)d_in[1];
  const float* gpw=(const float*)d_in[2];
  const float* g1g=(const float*)d_in[3];
  const float* g1b=(const float*)d_in[4];
  const float* g1m=(const float*)d_in[5];
  const float* g1v=(const float*)d_in[6];
  const float* gcw=(const float*)d_in[7];
  const float* g2g=(const float*)d_in[8];
  const float* g2b=(const float*)d_in[9];
  const float* g2m=(const float*)d_in[10];
  const float* g2v=(const float*)d_in[11];
  const float* sw1=(const float*)d_in[12];
  const float* sw2=(const float*)d_in[13];
  const float* prw=(const float*)d_in[14];
  const float* b3g=(const float*)d_in[15];
  const float* b3b=(const float*)d_in[16];
  const float* b3m=(const float*)d_in[17];
  const float* b3v=(const float*)d_in[18];
  const float* ipw=(const float*)d_in[19];
  const float* c1w=(const float*)d_in[20];
  const float* c1b=(const float*)d_in[21];
  const float* xpw=(const float*)d_in[22];
  const float* dtw=(const float*)d_in[23];
  const float* dtb=(const float*)d_in[24];
  const float* Alog=(const float*)d_in[25];
  const float* Dp=(const float*)d_in[26];
  const float* opw=(const float*)d_in[27];
  const float* piw=(const float*)d_in[28];
  const float* pib=(const float*)d_in[29];
  const float* fw=(const float*)d_in[30];

  char* w=(char*)d_ws;
  float* x1=(float*)(w);                                 // 64 MiB fp32
  float* x2=(float*)(w+(64ull<<20));                     // 64 MiB fp32
  unsigned short* uT=(unsigned short*)w;                 // aliases x1 (bf16, after k5)
  unsigned short* xsT=(unsigned short*)(w+(64ull<<20));  // aliases x2 (bf16, after k5)
  unsigned short* dtT=xsT;                               // aliases xsT (after k6b)
  unsigned short* Y4=xsT;                                // aliases dtT (after k7p2)
  unsigned short* zT=(unsigned short*)(w+(128ull<<20));  // 64 MiB bf16
  float* Fp=(float*)(w+(192ull<<20));                    // 16 MiB
  float* FpT=(float*)(w+(208ull<<20));                   // 16 MiB
  float* ysum=(float*)(w+(224ull<<20));                  // 16 MiB
  float* Bc=(float*)(w+(240ull<<20));                    // 512 KiB
  float* Cc=Bc+32*4096;                                  // 512 KiB
  float* sr=Cc+32*4096;                                  // 32 KiB
  float* sse=sr+8192;                                    // 32 KiB
  float* Pq=sse+8192;                                    // 512 KiB
  float* h0=Pq+131072;                                   // 256 KiB

  k1m<<<dim3(64,8,8),256,0,stream>>>(FT1,FT2,gpw,g1g,g1b,g1m,g1v,x1);
  k2<<<16384,256,0,stream>>>(x1,gcw,g2g,g2b,g2m,g2v,x2);
  k3<<<8192,256,0,stream>>>(x1,x2,sr);
  k4<<<8,256,0,stream>>>(sr,sw1,sw2,sse);
  k5m<<<dim3(64,2,8),256,0,stream>>>(x1,x2,sse,prw,b3g,b3b,b3m,b3v,Fp,FpT);
  k6am<<<dim3(64,8,32),256,0,stream>>>(Fp,FpT,ipw,xsT,zT);
  k6b<<<16384,256,0,stream>>>(xsT,c1w,c1b,uT);
  k6c<<<dim3(64,32),256,0,stream>>>(uT,xpw,dtw,dtb,dtT,Bc,Cc);
  k7p1<<<256,256,0,stream>>>(uT,dtT,Bc,Alog,Pq);
  k7mid<<<32,256,0,stream>>>(Pq,h0);
  k7p2<<<256,256,0,stream>>>(uT,dtT,zT,Bc,Cc,Alog,Dp,h0);
  k8am<<<dim3(64,2,32),256,0,stream>>>(uT,opw,Y4);
  k8bm<<<dim3(64,2,8),256,0,stream>>>(Fp,FpT,Y4,piw,pib,ysum);
  k9<<<dim3(64,2,8),256,0,stream>>>(ysum,Fp,fw,(float*)d_out);
}

// Round 4
// 904.320 us; speedup vs baseline: 2.1456x; 1.3094x over previous
//
#include <hip/hip_runtime.h>
#include <hip/hip_bf16.h>

#define DEV static __device__ __forceinline__

#define PIX 4096
#define SEQL 4096
#define BEPS 1e-5f

DEV float b2f(unsigned short u){ unsigned int i=((unsigned int)u)<<16; float f; __builtin_memcpy(&f,&i,4); return f; }
DEV unsigned short f2b(float f){ __hip_bfloat16 h=__float2bfloat16(f); unsigned short s; __builtin_memcpy(&s,&h,2); return s; }
DEV short f2bs(float f){ return (short)f2b(f); }
DEV void unp2(unsigned int w, float&a, float&b){ unsigned int lo=w<<16, hi=w&0xffff0000u; __builtin_memcpy(&a,&lo,4); __builtin_memcpy(&b,&hi,4); }
DEV unsigned int pk2(float a,float b){ return (unsigned int)f2b(a)|((unsigned int)f2b(b)<<16); }
DEV float sigm(float x){ return 1.f/(1.f+__expf(-x)); }
DEV float silu_(float x){ return x*sigm(x); }
DEV float softplus_(float x){ return (x>20.f)?x:log1pf(__expf(x)); }

using short8 = __attribute__((ext_vector_type(8))) short;
using f32x4  = __attribute__((ext_vector_type(4))) float;
#define MFMA16 __builtin_amdgcn_mfma_f32_16x16x32_bf16

// ================= MFMA GEMM skeleton =================
// tile 64(M) x 64(N) x 64(K), 256 threads = 4 waves (2x2), 2x2 16x16x32 frags/wave.
// BOTH sA and sW are [row][k] (72 shorts/row) with chunk-XOR swizzle:
//   element (r,k) at  r*72 + (((k>>4)^(r&3))<<4) + (k&15)
// -> all MFMA operand reads are ds_read_b128, rows 0-7 perfectly bank-spread, r/r+8 2-way (free).

#define MF_PRE() \
  const int tid=threadIdx.x; \
  const int lane=tid&63, wid=tid>>6; \
  const int wm=wid&1, wn=wid>>1; \
  const int fr=lane&15, fg=lane>>4; \
  const int srow=tid>>2, sch=tid&3; \
  const int tk=tid&63, tmb=(tid>>6)*16;

// stage one [m][k] row-chunk from a token-major source: 16 contiguous k at row srow
#define STAGE_A_TOK(EXPRF) { \
  union { short h[16]; uint4 q[2]; } tmpa; \
  _Pragma("unroll") for(int j=0;j<16;++j){ float v_=(EXPRF); tmpa.h[j]=f2bs(v_); } \
  int base_=srow*72+((sch^(srow&3))*16); \
  *(uint4*)&sA[base_]=tmpa.q[0]; *(uint4*)&sA[base_+8]=tmpa.q[1]; }

// transpose-stage from channel-major fp32: thread owns channel tk, 16 m at tmb
#define STAGE_A_TR_F32(EXPR16) { \
  float tv[16]; \
  _Pragma("unroll") for(int j=0;j<16;++j) tv[j]=(EXPR16); \
  _Pragma("unroll") for(int j=0;j<16;++j){ int m_=tmb+j; \
    sA[m_*72+(((tk>>4)^(m_&3))<<4)+(tk&15)]=f2bs(tv[j]); } }

// transpose-stage from channel-major bf16
#define STAGE_A_TR_BF(PTR) { \
  const unsigned short* ap_=(PTR); \
  unsigned short hv[16]; \
  *(uint4*)&hv[0]=*(const uint4*)ap_; *(uint4*)&hv[8]=*(const uint4*)(ap_+8); \
  _Pragma("unroll") for(int j=0;j<16;++j){ int m_=tmb+j; \
    sA[m_*72+(((tk>>4)^(m_&3))<<4)+(tk&15)]=(short)hv[j]; } }

#define STAGE_W(PTR,LDK) { \
  const float* wp_=(PTR)+(size_t)(n0+srow)*(LDK)+k0+sch*16; \
  union { short h[16]; uint4 q[2]; } tmpw; \
  _Pragma("unroll") \
  for(int j=0;j<16;++j) tmpw.h[j]=f2bs(wp_[j]); \
  int sw_=((sch^(srow&3))*16); \
  *(uint4*)&sW[srow*72+sw_]=tmpw.q[0]; \
  *(uint4*)&sW[srow*72+sw_+8]=tmpw.q[1]; }

#define MF_STEP() \
  _Pragma("unroll") \
  for(int kk=0;kk<64;kk+=32){ \
    short8 af[2],bfv[2]; const int kq_=kk+fg*8; \
    _Pragma("unroll") for(int i=0;i<2;++i){ int ml=wm*32+i*16+fr; \
      af[i]=*(const short8*)&sA[ml*72+(((kq_>>4)^(ml&3))<<4)+(kq_&15)]; } \
    _Pragma("unroll") for(int jn=0;jn<2;++jn){ int nl=wn*32+jn*16+fr; \
      bfv[jn]=*(const short8*)&sW[nl*72+(((kq_>>4)^(nl&3))<<4)+(kq_&15)]; } \
    _Pragma("unroll") for(int i=0;i<2;++i) \
      _Pragma("unroll") for(int jn=0;jn<2;++jn) \
        acc[i][jn]=MFMA16(af[i],bfv[jn],acc[i][jn],0,0,0); }

// ---------------- k1m: conv1x1 256->512 + BN + ReLU (MFMA) ----------------
__global__ __launch_bounds__(256) void k1m(const float* __restrict__ FT1,const float* __restrict__ FT2,
  const float* __restrict__ Wp,const float* __restrict__ gg,const float* __restrict__ gb,
  const float* __restrict__ gm,const float* __restrict__ gv,float* __restrict__ x1)
{
  MF_PRE();
  __shared__ __align__(16) short sA[64*72];
  __shared__ __align__(16) short sW[64*72];
  const int m0=blockIdx.x*64, n0=blockIdx.y*64, b=blockIdx.z;
  f32x4 acc[2][2]={};
  for(int k0=0;k0<256;k0+=64){
    { int c=k0+tk;
      const float* s_=(c<128)? FT1+((size_t)b*128+c)*PIX : FT2+((size_t)b*128+c-128)*PIX;
      const float* ap=s_+m0+tmb;
      STAGE_A_TR_F32(ap[j]); }
    STAGE_W(Wp,256);
    __syncthreads();
    MF_STEP();
    __syncthreads();
  }
  #pragma unroll
  for(int jn=0;jn<2;++jn){ int oc=n0+wn*32+jn*16+fr;
    float ks=gg[oc]*rsqrtf(gv[oc]+BEPS), kb=gb[oc]-gm[oc]*ks;
    #pragma unroll
    for(int i=0;i<2;++i){ int mb=m0+wm*32+i*16+fg*4;
      float4 v; v.x=fmaxf(acc[i][jn][0]*ks+kb,0.f); v.y=fmaxf(acc[i][jn][1]*ks+kb,0.f);
      v.z=fmaxf(acc[i][jn][2]*ks+kb,0.f); v.w=fmaxf(acc[i][jn][3]*ks+kb,0.f);
      *(float4*)&x1[((size_t)b*512+oc)*PIX+mb]=v; } }
}

// ---------------- k2: depthwise 3x3 + BN + ReLU ----------------
__global__ __launch_bounds__(256) void k2(const float* __restrict__ x1,const float* __restrict__ cw,
  const float* __restrict__ gg,const float* __restrict__ gb,const float* __restrict__ gm,
  const float* __restrict__ gv,float* __restrict__ x2)
{
  int gid=blockIdx.x*256+threadIdx.x;
  int wq=gid&15, h=(gid>>4)&63, bc=gid>>10;
  int c=bc&511;
  const float* src=x1+(size_t)bc*PIX;
  float wv[9];
  #pragma unroll
  for(int i=0;i<9;++i) wv[i]=cw[c*9+i];
  float ks=gg[c]*rsqrtf(gv[c]+BEPS), kb=gb[c]-gm[c]*ks;
  int wb=wq*4;
  float o[4]={};
  #pragma unroll
  for(int dh=0;dh<3;++dh){ int hh=h+dh-1; if(hh<0||hh>63) continue;
    const float* row=src+hh*64;
    float rv[6];
    #pragma unroll
    for(int j=0;j<6;++j){ int wc=wb-1+j; rv[j]=(wc>=0&&wc<64)?row[wc]:0.f; }
    #pragma unroll
    for(int dw=0;dw<3;++dw){ float wgt=wv[dh*3+dw];
      #pragma unroll
      for(int i=0;i<4;++i) o[i]+=rv[i+dw]*wgt; } }
  float4 v; v.x=fmaxf(o[0]*ks+kb,0.f); v.y=fmaxf(o[1]*ks+kb,0.f);
  v.z=fmaxf(o[2]*ks+kb,0.f); v.w=fmaxf(o[3]*ks+kb,0.f);
  *(float4*)&x2[(size_t)bc*PIX+h*64+wb]=v;
}

// ---------------- k3: SE mean ----------------
__global__ __launch_bounds__(256) void k3(const float* __restrict__ x1,const float* __restrict__ x2,
  float* __restrict__ sr)
{
  int bc=blockIdx.x; int cg=bc&1023, b=bc>>10;
  const float* src=(cg<512)? x1+((size_t)b*512+cg)*PIX : x2+((size_t)b*512+cg-512)*PIX;
  float s=0;
  for(int i=threadIdx.x;i<1024;i+=256){ float4 v=((const float4*)src)[i]; s+=v.x+v.y+v.z+v.w; }
  #pragma unroll
  for(int off=32;off;off>>=1) s+=__shfl_down(s,off);
  __shared__ float red[4];
  if((threadIdx.x&63)==0) red[threadIdx.x>>6]=s;
  __syncthreads();
  if(threadIdx.x==0) sr[bc]=(red[0]+red[1]+red[2]+red[3])*(1.f/4096.f);
}

// ---------------- k4: SE MLP ----------------
__global__ __launch_bounds__(256) void k4(const float* __restrict__ sr,const float* __restrict__ w1,
  const float* __restrict__ w2,float* __restrict__ sOut)
{
  int b=blockIdx.x;
  __shared__ float ls[1024];
  __shared__ float pm[4][64];
  __shared__ float mid[64];
  for(int i=threadIdx.x;i<1024;i+=256) ls[i]=sr[b*1024+i];
  __syncthreads();
  int k=threadIdx.x&63, part=threadIdx.x>>6;
  float p=0;
  for(int c=part*256;c<part*256+256;++c) p+=ls[c]*w1[k*1024+c];
  pm[part][k]=p;
  __syncthreads();
  if(threadIdx.x<64) mid[threadIdx.x]=fmaxf(pm[0][threadIdx.x]+pm[1][threadIdx.x]+pm[2][threadIdx.x]+pm[3][threadIdx.x],0.f);
  __syncthreads();
  for(int j=threadIdx.x;j<1024;j+=256){
    float a=0;
    for(int kk=0;kk<64;++kk) a+=mid[kk]*w2[j*64+kk];
    sOut[b*1024+j]=sigm(a);
  }
}

// ---------------- k5m: proj 1024->128 (+SE) + BN3 -> Fp, FpT TOKEN-major [b][t][128] ----------------
__global__ __launch_bounds__(256) void k5m(const float* __restrict__ x1,const float* __restrict__ x2,
  const float* __restrict__ sse,const float* __restrict__ Wp,
  const float* __restrict__ g3,const float* __restrict__ b3,const float* __restrict__ m3,
  const float* __restrict__ v3,float* __restrict__ Fp,float* __restrict__ FpT)
{
  MF_PRE();
  __shared__ __align__(16) short sA[64*72];
  __shared__ __align__(16) short sW[64*72];
  const int m0=blockIdx.x*64, n0=blockIdx.y*64, b=blockIdx.z;
  f32x4 acc[2][2]={};
  for(int k0=0;k0<1024;k0+=64){
    { int c=k0+tk;
      const float* s_=(c<512)? x1+((size_t)b*512+c)*PIX : x2+((size_t)b*512+c-512)*PIX;
      float sc=sse[b*1024+c];
      const float* ap=s_+m0+tmb;
      STAGE_A_TR_F32(ap[j]*sc); }
    STAGE_W(Wp,1024);
    __syncthreads();
    MF_STEP();
    __syncthreads();
  }
  #pragma unroll
  for(int jn=0;jn<2;++jn){ int oc=n0+wn*32+jn*16+fr;
    float ks=g3[oc]*rsqrtf(v3[oc]+BEPS), kb=b3[oc]-m3[oc]*ks;
    #pragma unroll
    for(int i=0;i<2;++i){ int mb=m0+wm*32+i*16+fg*4;
      #pragma unroll
      for(int p=0;p<4;++p){ int pp=mb+p; float val=acc[i][jn][p]*ks+kb;
        Fp[((size_t)b*PIX+pp)*128+oc]=val;
        int q=((pp&63)<<6)|(pp>>6);
        FpT[((size_t)b*PIX+q)*128+oc]=val; } } }
}

// ---------------- k6am: in_proj 128->512 -> xsT, zT [n][c][t] bf16 (MFMA, token-major A) ----------------
__global__ __launch_bounds__(256) void k6am(const float* __restrict__ Fp,const float* __restrict__ FpT,
  const float* __restrict__ Win,unsigned short* __restrict__ xsT,unsigned short* __restrict__ zT)
{
  MF_PRE();
  __shared__ __align__(16) short sA[64*72];
  __shared__ __align__(16) short sW[64*72];
  const int m0=blockIdx.x*64, n0=blockIdx.y*64, n=blockIdx.z;
  const int d=n>>3, b=n&7;
  const float* src=((d<2)?Fp:FpT)+(size_t)b*PIX*128;
  const int rev=(d&1)?63:0;
  f32x4 acc[2][2]={};
  for(int k0=0;k0<128;k0+=64){
    { int t=m0+srow; int tm=(t&~63)|((t&63)^rev);
      const float* ap=src+(size_t)tm*128+k0+sch*16;
      STAGE_A_TOK(ap[j]); }
    STAGE_W(Win,128);
    __syncthreads();
    MF_STEP();
    __syncthreads();
  }
  #pragma unroll
  for(int jn=0;jn<2;++jn){ int r=n0+wn*32+jn*16+fr;
    unsigned short* dst; int row; bool dosilu;
    if(r<256){ dst=xsT; row=r; dosilu=false; } else { dst=zT; row=r-256; dosilu=true; }
    #pragma unroll
    for(int i=0;i<2;++i){ int mb=m0+wm*32+i*16+fg*4;
      float v0=acc[i][jn][0],v1=acc[i][jn][1],v2=acc[i][jn][2],v3=acc[i][jn][3];
      if(dosilu){ v0=silu_(v0); v1=silu_(v1); v2=silu_(v2); v3=silu_(v3); }
      uint2 pk; pk.x=pk2(v0,v1); pk.y=pk2(v2,v3);
      *(uint2*)&dst[((size_t)n*256+row)*SEQL+mb]=pk; } }
}

// ---------------- k6b: causal conv1d (k=4) + SiLU ----------------
__global__ __launch_bounds__(256) void k6b(const unsigned short* __restrict__ xsT,
  const float* __restrict__ cw,const float* __restrict__ cb,unsigned short* __restrict__ uT)
{
  int gid=blockIdx.x*256+threadIdx.x;
  int tb=gid&511, nc=gid>>9, c=nc&255;
  const unsigned short* row=xsT+(size_t)nc*SEQL;
  int t0=tb*8;
  float w0=cw[c*4+0],w1=cw[c*4+1],w2=cw[c*4+2],w3=cw[c*4+3],bb=cb[c];
  float xv[11];
  #pragma unroll
  for(int j=0;j<11;++j){ int t=t0-3+j; xv[j]=(t>=0)?b2f(row[t]):0.f; }
  unsigned int ow[4];
  #pragma unroll
  for(int i=0;i<8;i+=2){
    float a0=xv[i]*w0+xv[i+1]*w1+xv[i+2]*w2+xv[i+3]*w3+bb;
    float a1=xv[i+1]*w0+xv[i+2]*w1+xv[i+3]*w2+xv[i+4]*w3+bb;
    ow[i>>1]=pk2(silu_(a0),silu_(a1));
  }
  *(uint4*)&uT[(size_t)nc*SEQL+t0]=make_uint4(ow[0],ow[1],ow[2],ow[3]);
}

// ---------------- k6c: x_proj (10) + dt_proj + softplus -> dtT, Bc, Cc ----------------
__global__ __launch_bounds__(256) void k6c(const unsigned short* __restrict__ uT,
  const float* __restrict__ xpw,const float* __restrict__ dtw,const float* __restrict__ dtb,
  unsigned short* __restrict__ dtT,float* __restrict__ Bc,float* __restrict__ Cc)
{
  __shared__ unsigned short sU[64][64];
  __shared__ float sDbl[64][11];
  const int tid=threadIdx.x, tt=tid&63, kg=tid>>6;
  const int t0=blockIdx.x*64, n=blockIdx.y;
  const int ka=kg, kb_=kg+4, kc=kg+8;
  float a0=0,a1=0,a2=0;
  for(int cb=0;cb<4;++cb){
    for(int l=tid;l<4096;l+=256){ int cc=l>>6, t=l&63;
      sU[cc][t]=uT[((size_t)n*256+cb*64+cc)*SEQL+t0+t]; }
    __syncthreads();
    for(int cc=0;cc<64;++cc){
      float uv=b2f(sU[cc][tt]);
      int c=cb*64+cc;
      a0+=uv*xpw[ka*256+c];
      a1+=uv*xpw[kb_*256+c];
      if(kc<10) a2+=uv*xpw[kc*256+c];
    }
    __syncthreads();
  }
  sDbl[tt][ka]=a0; sDbl[tt][kb_]=a1; if(kg<2) sDbl[tt][kc]=a2;
  __syncthreads();
  if(kg==0) Bc[(size_t)n*SEQL+t0+tt]=sDbl[tt][8];
  else if(kg==1) Cc[(size_t)n*SEQL+t0+tt]=sDbl[tt][9];
  float d8[8];
  #pragma unroll
  for(int i=0;i<8;++i) d8[i]=sDbl[tt][i];
  for(int j=0;j<64;++j){
    int c=kg*64+j;
    float a=dtb[c];
    #pragma unroll
    for(int i=0;i<8;++i) a+=d8[i]*dtw[c*8+i];
    dtT[((size_t)n*256+c)*SEQL+t0+tt]=f2b(softplus_(a));
  }
}

// ---------------- k7: chunked scan (8 chunks of 512) ----------------
__global__ __launch_bounds__(256) void k7p1(const unsigned short* __restrict__ uT,
  const unsigned short* __restrict__ dtT,const float* __restrict__ Bc,
  const float* __restrict__ A_log,float* __restrict__ Pq)
{
  int g=blockIdx.x*256+threadIdx.x;
  int ch=g&7, nc=g>>3, c=nc&255, n=nc>>8;
  float A=-__expf(A_log[c]);
  size_t base=(size_t)nc*SEQL+ch*512;
  const float* bp=Bc+(size_t)n*SEQL+ch*512;
  float P=1.f,q=0.f;
  for(int t0=0;t0<512;t0+=8){
    uint4 uu=*(const uint4*)&uT[base+t0];
    uint4 dd=*(const uint4*)&dtT[base+t0];
    float uv[8],dv[8];
    unp2(uu.x,uv[0],uv[1]);unp2(uu.y,uv[2],uv[3]);unp2(uu.z,uv[4],uv[5]);unp2(uu.w,uv[6],uv[7]);
    unp2(dd.x,dv[0],dv[1]);unp2(dd.y,dv[2],dv[3]);unp2(dd.z,dv[4],dv[5]);unp2(dd.w,dv[6],dv[7]);
    #pragma unroll
    for(int i=0;i<8;++i){
      float e=__expf(dv[i]*A);
      q=q*e+dv[i]*bp[t0+i]*uv[i];
      P*=e;
    }
  }
  Pq[(size_t)g*2]=P; Pq[(size_t)g*2+1]=q;
}

__global__ __launch_bounds__(256) void k7mid(const float* __restrict__ Pq,float* __restrict__ h0)
{
  int nc=blockIdx.x*256+threadIdx.x;
  float h=0.f;
  #pragma unroll
  for(int k=0;k<8;++k){
    h0[(size_t)nc*8+k]=h;
    h=h*Pq[((size_t)nc*8+k)*2]+Pq[((size_t)nc*8+k)*2+1];
  }
}

__global__ __launch_bounds__(256) void k7p2(unsigned short* __restrict__ uT,
  const unsigned short* __restrict__ dtT,const unsigned short* __restrict__ zT,
  const float* __restrict__ Bc,const float* __restrict__ Cc,
  const float* __restrict__ A_log,const float* __restrict__ Dp,
  const float* __restrict__ h0)
{
  int g=blockIdx.x*256+threadIdx.x;
  int ch=g&7, nc=g>>3, c=nc&255, n=nc>>8;
  float A=-__expf(A_log[c]), Dv=Dp[c];
  size_t base=(size_t)nc*SEQL+ch*512;
  const float* bp=Bc+(size_t)n*SEQL+ch*512;
  const float* cp=Cc+(size_t)n*SEQL+ch*512;
  float h=h0[g];
  for(int t0=0;t0<512;t0+=8){
    uint4 uu=*(const uint4*)&uT[base+t0];
    uint4 dd=*(const uint4*)&dtT[base+t0];
    uint4 zz=*(const uint4*)&zT[base+t0];
    float uv[8],dv[8],zv[8],yv[8];
    unp2(uu.x,uv[0],uv[1]);unp2(uu.y,uv[2],uv[3]);unp2(uu.z,uv[4],uv[5]);unp2(uu.w,uv[6],uv[7]);
    unp2(dd.x,dv[0],dv[1]);unp2(dd.y,dv[2],dv[3]);unp2(dd.z,dv[4],dv[5]);unp2(dd.w,dv[6],dv[7]);
    unp2(zz.x,zv[0],zv[1]);unp2(zz.y,zv[2],zv[3]);unp2(zz.z,zv[4],zv[5]);unp2(zz.w,zv[6],zv[7]);
    #pragma unroll
    for(int i=0;i<8;++i){
      float e=__expf(dv[i]*A);
      h=h*e+dv[i]*bp[t0+i]*uv[i];
      yv[i]=(h*cp[t0+i]+uv[i]*Dv)*zv[i];
    }
    uint4 oo; oo.x=pk2(yv[0],yv[1]); oo.y=pk2(yv[2],yv[3]); oo.z=pk2(yv[4],yv[5]); oo.w=pk2(yv[6],yv[7]);
    *(uint4*)&uT[base+t0]=oo;
  }
}

// ---------------- k8am: out_proj 256->128 -> Y4 [n][oc][t] bf16 (MFMA, transpose-staged A) ----------------
__global__ __launch_bounds__(256) void k8am(const unsigned short* __restrict__ yT,
  const float* __restrict__ Wout,unsigned short* __restrict__ Y4)
{
  MF_PRE();
  __shared__ __align__(16) short sA[64*72];
  __shared__ __align__(16) short sW[64*72];
  const int m0=blockIdx.x*64, n0=blockIdx.y*64, n=blockIdx.z;
  const unsigned short* ybase=yT+(size_t)n*256*SEQL;
  f32x4 acc[2][2]={};
  for(int k0=0;k0<256;k0+=64){
    { int c=k0+tk;
      STAGE_A_TR_BF(ybase+(size_t)c*SEQL+m0+tmb); }
    STAGE_W(Wout,256);
    __syncthreads();
    MF_STEP();
    __syncthreads();
  }
  #pragma unroll
  for(int jn=0;jn<2;++jn){ int oc=n0+wn*32+jn*16+fr;
    #pragma unroll
    for(int i=0;i<2;++i){ int mb=m0+wm*32+i*16+fg*4;
      uint2 pk; pk.x=pk2(acc[i][jn][0],acc[i][jn][1]); pk.y=pk2(acc[i][jn][2],acc[i][jn][3]);
      *(uint2*)&Y4[((size_t)n*128+oc)*SEQL+mb]=pk; } }
}

// ---------------- k8bm: pi GEMM + sigmoid gate + 4-dir sum -> ysum TOKEN-major [b][t][128] ----------------
__global__ __launch_bounds__(256) void k8bm(const float* __restrict__ Fp,const float* __restrict__ FpT,
  const unsigned short* __restrict__ Y4,const float* __restrict__ piw,const float* __restrict__ pib,
  float* __restrict__ ysum)
{
  MF_PRE();
  __shared__ __align__(16) short sA[64*72];
  __shared__ __align__(16) short sW[64*72];
  const int m0=blockIdx.x*64, n0=blockIdx.y*64, b=blockIdx.z;
  f32x4 gs[2][2]={};
  for(int d=0;d<4;++d){
    const int n=d*8+b;
    const float* src=((d<2)?Fp:FpT)+(size_t)b*PIX*128;
    const int rev=(d&1)?63:0;
    f32x4 acc[2][2]={};
    for(int k0=0;k0<256;k0+=64){
      if(k0<128){
        int t=m0+srow; int tm=(t&~63)|((t&63)^rev);
        const float* ap=src+(size_t)tm*128+k0+sch*16;
        STAGE_A_TOK(ap[j]);
      } else {
        int c=k0-128+tk;
        STAGE_A_TR_BF(Y4+((size_t)n*128+c)*SEQL+m0+tmb);
      }
      STAGE_W(piw,256);
      __syncthreads();
      MF_STEP();
      __syncthreads();
    }
    #pragma unroll
    for(int i=0;i<2;++i){
      #pragma unroll
      for(int jn=0;jn<2;++jn){
        int oc=n0+wn*32+jn*16+fr;
        int mb=m0+wm*32+i*16+fg*4;
        float pb=pib[oc];
        const unsigned short* yrow=Y4+((size_t)n*128+oc)*SEQL;
        #pragma unroll
        for(int p=0;p<4;++p){
          int t=mb+p; int tm=(t&~63)|((t&63)^rev);
          float pi=sigm(acc[i][jn][p]+pb);
          float x4=src[(size_t)tm*128+oc];
          float y4=b2f(yrow[t]);
          gs[i][jn][p]+=y4*pi+x4*(1.f-pi);
        }
      }
    }
  }
  #pragma unroll
  for(int i=0;i<2;++i)
    #pragma unroll
    for(int jn=0;jn<2;++jn){
      int oc=n0+wn*32+jn*16+fr;
      int mb=m0+wm*32+i*16+fg*4;
      #pragma unroll
      for(int p=0;p<4;++p)
        ysum[((size_t)b*PIX+mb+p)*128+oc]=gs[i][jn][p];
    }
}

// ---------------- k9m: final conv1x1 ((ysum+Fp) @ fw) (MFMA, token-major A) ----------------
__global__ __launch_bounds__(256) void k9m(const float* __restrict__ ysum,const float* __restrict__ Fp,
  const float* __restrict__ fw,float* __restrict__ out)
{
  MF_PRE();
  __shared__ __align__(16) short sA[64*72];
  __shared__ __align__(16) short sW[64*72];
  const int m0=blockIdx.x*64, n0=blockIdx.y*64, b=blockIdx.z;
  f32x4 acc[2][2]={};
  for(int k0=0;k0<128;k0+=64){
    { int t=m0+srow;
      const float* a1=ysum+((size_t)b*PIX+t)*128+k0+sch*16;
      const float* a2=Fp  +((size_t)b*PIX+t)*128+k0+sch*16;
      STAGE_A_TOK(a1[j]+a2[j]); }
    STAGE_W(fw,128);
    __syncthreads();
    MF_STEP();
    __syncthreads();
  }
  #pragma unroll
  for(int jn=0;jn<2;++jn){ int oc=n0+wn*32+jn*16+fr;
    #pragma unroll
    for(int i=0;i<2;++i){ int mb=m0+wm*32+i*16+fg*4;
      *(float4*)&out[((size_t)b*128+oc)*PIX+mb]=
        make_float4(acc[i][jn][0],acc[i][jn][1],acc[i][jn][2],acc[i][jn][3]); } }
}

extern "C" void kernel_launch(void* const* d_in,const int* in_sizes,int n_in,
  void* d_out,int out_size,void* d_ws,size_t ws_size,hipStream_t stream)
{
  (void)in_sizes; (void)n_in; (void)out_size; (void)ws_size;
  const float* FT1=(const float*)d_in[0];
  const float* FT2=(const float*)d_in[1];
  const float* gpw=(const float*)d_in[2];
  const float* g1g=(const float*)d_in[3];
  const float* g1b=(const float*)d_in[4];
  const float* g1m=(const float*)d_in[5];
  const float* g1v=(const float*)d_in[6];
  const float* gcw=(const float*)d_in[7];
  const float* g2g=(const float*)d_in[8];
  const float* g2b=(const float*)d_in[9];
  const float* g2m=(const float*)d_in[10];
  const float* g2v=(const float*)d_in[11];
  const float* sw1=(const float*)d_in[12];
  const float* sw2=(const float*)d_in[13];
  const float* prw=(const float*)d_in[14];
  const float* b3g=(const float*)d_in[15];
  const float* b3b=(const float*)d_in[16];
  const float* b3m=(const float*)d_in[17];
  const float* b3v=(const float*)d_in[18];
  const float* ipw=(const float*)d_in[19];
  const float* c1w=(const float*)d_in[20];
  const float* c1b=(const float*)d_in[21];
  const float* xpw=(const float*)d_in[22];
  const float* dtw=(const float*)d_in[23];
  const float* dtb=(const float*)d_in[24];
  const float* Alog=(const float*)d_in[25];
  const float* Dp=(const float*)d_in[26];
  const float* opw=(const float*)d_in[27];
  const float* piw=(const float*)d_in[28];
  const float* pib=(const float*)d_in[29];
  const float* fw=(const float*)d_in[30];

  char* w=(char*)d_ws;
  float* x1=(float*)(w);                                 // 64 MiB fp32
  float* x2=(float*)(w+(64ull<<20));                     // 64 MiB fp32
  unsigned short* uT=(unsigned short*)w;                 // aliases x1 (bf16, after k5)
  unsigned short* xsT=(unsigned short*)(w+(64ull<<20));  // aliases x2 (bf16, after k5)
  unsigned short* dtT=xsT;                               // aliases xsT (after k6b)
  unsigned short* Y4=xsT;                                // aliases dtT (after k7p2)
  unsigned short* zT=(unsigned short*)(w+(128ull<<20));  // 64 MiB bf16
  float* Fp=(float*)(w+(192ull<<20));                    // 16 MiB (token-major)
  float* FpT=(float*)(w+(208ull<<20));                   // 16 MiB (token-major)
  float* ysum=(float*)(w+(224ull<<20));                  // 16 MiB (token-major)
  float* Bc=(float*)(w+(240ull<<20));                    // 512 KiB
  float* Cc=Bc+32*4096;                                  // 512 KiB
  float* sr=Cc+32*4096;                                  // 32 KiB
  float* sse=sr+8192;                                    // 32 KiB
  float* Pq=sse+8192;                                    // 512 KiB
  float* h0=Pq+131072;                                   // 256 KiB

  k1m<<<dim3(64,8,8),256,0,stream>>>(FT1,FT2,gpw,g1g,g1b,g1m,g1v,x1);
  k2<<<16384,256,0,stream>>>(x1,gcw,g2g,g2b,g2m,g2v,x2);
  k3<<<8192,256,0,stream>>>(x1,x2,sr);
  k4<<<8,256,0,stream>>>(sr,sw1,sw2,sse);
  k5m<<<dim3(64,2,8),256,0,stream>>>(x1,x2,sse,prw,b3g,b3b,b3m,b3v,Fp,FpT);
  k6am<<<dim3(64,8,32),256,0,stream>>>(Fp,FpT,ipw,xsT,zT);
  k6b<<<16384,256,0,stream>>>(xsT,c1w,c1b,uT);
  k6c<<<dim3(64,32),256,0,stream>>>(uT,xpw,dtw,dtb,dtT,Bc,Cc);
  k7p1<<<256,256,0,stream>>>(uT,dtT,Bc,Alog,Pq);
  k7mid<<<32,256,0,stream>>>(Pq,h0);
  k7p2<<<256,256,0,stream>>>(uT,dtT,zT,Bc,Cc,Alog,Dp,h0);
  k8am<<<dim3(64,2,32),256,0,stream>>>(uT,opw,Y4);
  k8bm<<<dim3(64,2,8),256,0,stream>>>(Fp,FpT,Y4,piw,pib,ysum);
  k9m<<<dim3(64,2,8),256,0,stream>>>(ysum,Fp,fw,(float*)d_out);
}

// Round 5
// 870.038 us; speedup vs baseline: 2.2302x; 1.0394x over previous
//
#include <hip/hip_runtime.h>
#include <hip/hip_bf16.h>

#define DEV static __device__ __forceinline__

#define PIX 4096
#define SEQL 4096
#define BEPS 1e-5f

DEV float b2f(unsigned short u){ unsigned int i=((unsigned int)u)<<16; float f; __builtin_memcpy(&f,&i,4); return f; }
DEV unsigned short f2b(float f){ __hip_bfloat16 h=__float2bfloat16(f); unsigned short s; __builtin_memcpy(&s,&h,2); return s; }
DEV short f2bs(float f){ return (short)f2b(f); }
DEV void unp2(unsigned int w, float&a, float&b){ unsigned int lo=w<<16, hi=w&0xffff0000u; __builtin_memcpy(&a,&lo,4); __builtin_memcpy(&b,&hi,4); }
DEV unsigned int pk2(float a,float b){ return (unsigned int)f2b(a)|((unsigned int)f2b(b)<<16); }
DEV float sigm(float x){ return 1.f/(1.f+__expf(-x)); }
DEV float silu_(float x){ return x*sigm(x); }
DEV float softplus_(float x){ return (x>20.f)?x:log1pf(__expf(x)); }

using short8 = __attribute__((ext_vector_type(8))) short;
using f32x4  = __attribute__((ext_vector_type(4))) float;
#define MFMA16 __builtin_amdgcn_mfma_f32_16x16x32_bf16

// ================= MFMA GEMM skeleton =================
// tile 64(M) x 64(N) x 64(K), 256 threads = 4 waves (2x2), 2x2 16x16x32 frags/wave.
// BOTH sA and sW are [row][k] (72 shorts/row) with chunk-XOR swizzle:
//   element (r,k) at  r*72 + (((k>>4)^(r&3))<<4) + (k&15)
// -> all MFMA operand reads are ds_read_b128, rows 0-7 perfectly bank-spread, r/r+8 2-way (free).

#define MF_PRE() \
  const int tid=threadIdx.x; \
  const int lane=tid&63, wid=tid>>6; \
  const int wm=wid&1, wn=wid>>1; \
  const int fr=lane&15, fg=lane>>4; \
  const int srow=tid>>2, sch=tid&3; \
  const int tk=tid&63, tmb=(tid>>6)*16;

// stage one [m][k] row-chunk from a token-major source: 16 contiguous k at row srow
#define STAGE_A_TOK(EXPRF) { \
  union { short h[16]; uint4 q[2]; } tmpa; \
  _Pragma("unroll") for(int j=0;j<16;++j){ float v_=(EXPRF); tmpa.h[j]=f2bs(v_); } \
  int base_=srow*72+((sch^(srow&3))*16); \
  *(uint4*)&sA[base_]=tmpa.q[0]; *(uint4*)&sA[base_+8]=tmpa.q[1]; }

// transpose-stage from channel-major fp32: thread owns channel tk, 16 m at tmb
#define STAGE_A_TR_F32(EXPR16) { \
  float tv[16]; \
  _Pragma("unroll") for(int j=0;j<16;++j) tv[j]=(EXPR16); \
  _Pragma("unroll") for(int j=0;j<16;++j){ int m_=tmb+j; \
    sA[m_*72+(((tk>>4)^(m_&3))<<4)+(tk&15)]=f2bs(tv[j]); } }

// transpose-stage from channel-major bf16
#define STAGE_A_TR_BF(PTR) { \
  const unsigned short* ap_=(PTR); \
  unsigned short hv[16]; \
  *(uint4*)&hv[0]=*(const uint4*)ap_; *(uint4*)&hv[8]=*(const uint4*)(ap_+8); \
  _Pragma("unroll") for(int j=0;j<16;++j){ int m_=tmb+j; \
    sA[m_*72+(((tk>>4)^(m_&3))<<4)+(tk&15)]=(short)hv[j]; } }

#define STAGE_W(PTR,LDK) { \
  const float* wp_=(PTR)+(size_t)(n0+srow)*(LDK)+k0+sch*16; \
  union { short h[16]; uint4 q[2]; } tmpw; \
  _Pragma("unroll") \
  for(int j=0;j<16;++j) tmpw.h[j]=f2bs(wp_[j]); \
  int sw_=((sch^(srow&3))*16); \
  *(uint4*)&sW[srow*72+sw_]=tmpw.q[0]; \
  *(uint4*)&sW[srow*72+sw_+8]=tmpw.q[1]; }

#define MF_STEP() \
  _Pragma("unroll") \
  for(int kk=0;kk<64;kk+=32){ \
    short8 af[2],bfv[2]; const int kq_=kk+fg*8; \
    _Pragma("unroll") for(int i=0;i<2;++i){ int ml=wm*32+i*16+fr; \
      af[i]=*(const short8*)&sA[ml*72+(((kq_>>4)^(ml&3))<<4)+(kq_&15)]; } \
    _Pragma("unroll") for(int jn=0;jn<2;++jn){ int nl=wn*32+jn*16+fr; \
      bfv[jn]=*(const short8*)&sW[nl*72+(((kq_>>4)^(nl&3))<<4)+(kq_&15)]; } \
    _Pragma("unroll") for(int i=0;i<2;++i) \
      _Pragma("unroll") for(int jn=0;jn<2;++jn) \
        acc[i][jn]=MFMA16(af[i],bfv[jn],acc[i][jn],0,0,0); }

// ---------------- k1m: conv1x1 256->512 + BN + ReLU (MFMA) ----------------
__global__ __launch_bounds__(256) void k1m(const float* __restrict__ FT1,const float* __restrict__ FT2,
  const float* __restrict__ Wp,const float* __restrict__ gg,const float* __restrict__ gb,
  const float* __restrict__ gm,const float* __restrict__ gv,float* __restrict__ x1)
{
  MF_PRE();
  __shared__ __align__(16) short sA[64*72];
  __shared__ __align__(16) short sW[64*72];
  const int m0=blockIdx.x*64, n0=blockIdx.y*64, b=blockIdx.z;
  f32x4 acc[2][2]={};
  for(int k0=0;k0<256;k0+=64){
    { int c=k0+tk;
      const float* s_=(c<128)? FT1+((size_t)b*128+c)*PIX : FT2+((size_t)b*128+c-128)*PIX;
      const float* ap=s_+m0+tmb;
      STAGE_A_TR_F32(ap[j]); }
    STAGE_W(Wp,256);
    __syncthreads();
    MF_STEP();
    __syncthreads();
  }
  #pragma unroll
  for(int jn=0;jn<2;++jn){ int oc=n0+wn*32+jn*16+fr;
    float ks=gg[oc]*rsqrtf(gv[oc]+BEPS), kb=gb[oc]-gm[oc]*ks;
    #pragma unroll
    for(int i=0;i<2;++i){ int mb=m0+wm*32+i*16+fg*4;
      float4 v; v.x=fmaxf(acc[i][jn][0]*ks+kb,0.f); v.y=fmaxf(acc[i][jn][1]*ks+kb,0.f);
      v.z=fmaxf(acc[i][jn][2]*ks+kb,0.f); v.w=fmaxf(acc[i][jn][3]*ks+kb,0.f);
      *(float4*)&x1[((size_t)b*512+oc)*PIX+mb]=v; } }
}

// ---------------- k2: depthwise 3x3 + BN + ReLU ----------------
__global__ __launch_bounds__(256) void k2(const float* __restrict__ x1,const float* __restrict__ cw,
  const float* __restrict__ gg,const float* __restrict__ gb,const float* __restrict__ gm,
  const float* __restrict__ gv,float* __restrict__ x2)
{
  int gid=blockIdx.x*256+threadIdx.x;
  int wq=gid&15, h=(gid>>4)&63, bc=gid>>10;
  int c=bc&511;
  const float* src=x1+(size_t)bc*PIX;
  float wv[9];
  #pragma unroll
  for(int i=0;i<9;++i) wv[i]=cw[c*9+i];
  float ks=gg[c]*rsqrtf(gv[c]+BEPS), kb=gb[c]-gm[c]*ks;
  int wb=wq*4;
  float o[4]={};
  #pragma unroll
  for(int dh=0;dh<3;++dh){ int hh=h+dh-1; if(hh<0||hh>63) continue;
    const float* row=src+hh*64;
    float rv[6];
    #pragma unroll
    for(int j=0;j<6;++j){ int wc=wb-1+j; rv[j]=(wc>=0&&wc<64)?row[wc]:0.f; }
    #pragma unroll
    for(int dw=0;dw<3;++dw){ float wgt=wv[dh*3+dw];
      #pragma unroll
      for(int i=0;i<4;++i) o[i]+=rv[i+dw]*wgt; } }
  float4 v; v.x=fmaxf(o[0]*ks+kb,0.f); v.y=fmaxf(o[1]*ks+kb,0.f);
  v.z=fmaxf(o[2]*ks+kb,0.f); v.w=fmaxf(o[3]*ks+kb,0.f);
  *(float4*)&x2[(size_t)bc*PIX+h*64+wb]=v;
}

// ---------------- k3: SE mean ----------------
__global__ __launch_bounds__(256) void k3(const float* __restrict__ x1,const float* __restrict__ x2,
  float* __restrict__ sr)
{
  int bc=blockIdx.x; int cg=bc&1023, b=bc>>10;
  const float* src=(cg<512)? x1+((size_t)b*512+cg)*PIX : x2+((size_t)b*512+cg-512)*PIX;
  float s=0;
  for(int i=threadIdx.x;i<1024;i+=256){ float4 v=((const float4*)src)[i]; s+=v.x+v.y+v.z+v.w; }
  #pragma unroll
  for(int off=32;off;off>>=1) s+=__shfl_down(s,off);
  __shared__ float red[4];
  if((threadIdx.x&63)==0) red[threadIdx.x>>6]=s;
  __syncthreads();
  if(threadIdx.x==0) sr[bc]=(red[0]+red[1]+red[2]+red[3])*(1.f/4096.f);
}

// ---------------- k4: SE MLP ----------------
__global__ __launch_bounds__(256) void k4(const float* __restrict__ sr,const float* __restrict__ w1,
  const float* __restrict__ w2,float* __restrict__ sOut)
{
  int b=blockIdx.x;
  __shared__ float ls[1024];
  __shared__ float pm[4][64];
  __shared__ float mid[64];
  for(int i=threadIdx.x;i<1024;i+=256) ls[i]=sr[b*1024+i];
  __syncthreads();
  int k=threadIdx.x&63, part=threadIdx.x>>6;
  float p=0;
  for(int c=part*256;c<part*256+256;++c) p+=ls[c]*w1[k*1024+c];
  pm[part][k]=p;
  __syncthreads();
  if(threadIdx.x<64) mid[threadIdx.x]=fmaxf(pm[0][threadIdx.x]+pm[1][threadIdx.x]+pm[2][threadIdx.x]+pm[3][threadIdx.x],0.f);
  __syncthreads();
  for(int j=threadIdx.x;j<1024;j+=256){
    float a=0;
    for(int kk=0;kk<64;++kk) a+=mid[kk]*w2[j*64+kk];
    sOut[b*1024+j]=sigm(a);
  }
}

// ---------------- k5m: proj 1024->128 (+SE) + BN3 -> Fp, FpT TOKEN-major [b][t][128] ----------------
__global__ __launch_bounds__(256) void k5m(const float* __restrict__ x1,const float* __restrict__ x2,
  const float* __restrict__ sse,const float* __restrict__ Wp,
  const float* __restrict__ g3,const float* __restrict__ b3,const float* __restrict__ m3,
  const float* __restrict__ v3,float* __restrict__ Fp,float* __restrict__ FpT)
{
  MF_PRE();
  __shared__ __align__(16) short sA[64*72];
  __shared__ __align__(16) short sW[64*72];
  const int m0=blockIdx.x*64, n0=blockIdx.y*64, b=blockIdx.z;
  f32x4 acc[2][2]={};
  for(int k0=0;k0<1024;k0+=64){
    { int c=k0+tk;
      const float* s_=(c<512)? x1+((size_t)b*512+c)*PIX : x2+((size_t)b*512+c-512)*PIX;
      float sc=sse[b*1024+c];
      const float* ap=s_+m0+tmb;
      STAGE_A_TR_F32(ap[j]*sc); }
    STAGE_W(Wp,1024);
    __syncthreads();
    MF_STEP();
    __syncthreads();
  }
  #pragma unroll
  for(int jn=0;jn<2;++jn){ int oc=n0+wn*32+jn*16+fr;
    float ks=g3[oc]*rsqrtf(v3[oc]+BEPS), kb=b3[oc]-m3[oc]*ks;
    #pragma unroll
    for(int i=0;i<2;++i){ int mb=m0+wm*32+i*16+fg*4;
      #pragma unroll
      for(int p=0;p<4;++p){ int pp=mb+p; float val=acc[i][jn][p]*ks+kb;
        Fp[((size_t)b*PIX+pp)*128+oc]=val;
        int q=((pp&63)<<6)|(pp>>6);
        FpT[((size_t)b*PIX+q)*128+oc]=val; } } }
}

// ---------------- k6am: in_proj 128->512 -> xsT, zT [n][c][t] bf16 (MFMA, token-major A) ----------------
__global__ __launch_bounds__(256) void k6am(const float* __restrict__ Fp,const float* __restrict__ FpT,
  const float* __restrict__ Win,unsigned short* __restrict__ xsT,unsigned short* __restrict__ zT)
{
  MF_PRE();
  __shared__ __align__(16) short sA[64*72];
  __shared__ __align__(16) short sW[64*72];
  const int m0=blockIdx.x*64, n0=blockIdx.y*64, n=blockIdx.z;
  const int d=n>>3, b=n&7;
  const float* src=((d<2)?Fp:FpT)+(size_t)b*PIX*128;
  const int rev=(d&1)?63:0;
  f32x4 acc[2][2]={};
  for(int k0=0;k0<128;k0+=64){
    { int t=m0+srow; int tm=(t&~63)|((t&63)^rev);
      const float* ap=src+(size_t)tm*128+k0+sch*16;
      STAGE_A_TOK(ap[j]); }
    STAGE_W(Win,128);
    __syncthreads();
    MF_STEP();
    __syncthreads();
  }
  #pragma unroll
  for(int jn=0;jn<2;++jn){ int r=n0+wn*32+jn*16+fr;
    unsigned short* dst; int row; bool dosilu;
    if(r<256){ dst=xsT; row=r; dosilu=false; } else { dst=zT; row=r-256; dosilu=true; }
    #pragma unroll
    for(int i=0;i<2;++i){ int mb=m0+wm*32+i*16+fg*4;
      float v0=acc[i][jn][0],v1=acc[i][jn][1],v2=acc[i][jn][2],v3=acc[i][jn][3];
      if(dosilu){ v0=silu_(v0); v1=silu_(v1); v2=silu_(v2); v3=silu_(v3); }
      uint2 pk; pk.x=pk2(v0,v1); pk.y=pk2(v2,v3);
      *(uint2*)&dst[((size_t)n*256+row)*SEQL+mb]=pk; } }
}

// ---------------- k6b: causal conv1d (k=4) + SiLU ----------------
__global__ __launch_bounds__(256) void k6b(const unsigned short* __restrict__ xsT,
  const float* __restrict__ cw,const float* __restrict__ cb,unsigned short* __restrict__ uT)
{
  int gid=blockIdx.x*256+threadIdx.x;
  int tb=gid&511, nc=gid>>9, c=nc&255;
  const unsigned short* row=xsT+(size_t)nc*SEQL;
  int t0=tb*8;
  float w0=cw[c*4+0],w1=cw[c*4+1],w2=cw[c*4+2],w3=cw[c*4+3],bb=cb[c];
  float xv[11];
  #pragma unroll
  for(int j=0;j<11;++j){ int t=t0-3+j; xv[j]=(t>=0)?b2f(row[t]):0.f; }
  unsigned int ow[4];
  #pragma unroll
  for(int i=0;i<8;i+=2){
    float a0=xv[i]*w0+xv[i+1]*w1+xv[i+2]*w2+xv[i+3]*w3+bb;
    float a1=xv[i+1]*w0+xv[i+2]*w1+xv[i+3]*w2+xv[i+4]*w3+bb;
    ow[i>>1]=pk2(silu_(a0),silu_(a1));
  }
  *(uint4*)&uT[(size_t)nc*SEQL+t0]=make_uint4(ow[0],ow[1],ow[2],ow[3]);
}

// ---------------- kWc: Wc = dtw @ xpw[0:8]  (256x256 fp32) ----------------
__global__ __launch_bounds__(256) void kWc(const float* __restrict__ dtw,const float* __restrict__ xpw,
  float* __restrict__ Wc)
{
  int c=blockIdx.x, k=threadIdx.x;
  float a=0.f;
  #pragma unroll
  for(int i=0;i<8;++i) a+=dtw[c*8+i]*xpw[i*256+k];
  Wc[c*256+k]=a;
}

// ---------------- k6cm: dt GEMM 256->256 (u @ Wc.T) + bias + softplus -> dtT [n][c][t] ----------------
__global__ __launch_bounds__(256) void k6cm(const unsigned short* __restrict__ uT,
  const float* __restrict__ Wc,const float* __restrict__ dtb,
  unsigned short* __restrict__ dtT)
{
  MF_PRE();
  __shared__ __align__(16) short sA[64*72];
  __shared__ __align__(16) short sW[64*72];
  const int m0=blockIdx.x*64, n0=blockIdx.y*64, n=blockIdx.z;
  const unsigned short* ubase=uT+(size_t)n*256*SEQL;
  f32x4 acc[2][2]={};
  for(int k0=0;k0<256;k0+=64){
    { int c=k0+tk;
      STAGE_A_TR_BF(ubase+(size_t)c*SEQL+m0+tmb); }
    STAGE_W(Wc,256);
    __syncthreads();
    MF_STEP();
    __syncthreads();
  }
  #pragma unroll
  for(int jn=0;jn<2;++jn){ int oc=n0+wn*32+jn*16+fr;
    float bias=dtb[oc];
    #pragma unroll
    for(int i=0;i<2;++i){ int mb=m0+wm*32+i*16+fg*4;
      float v0=softplus_(acc[i][jn][0]+bias);
      float v1=softplus_(acc[i][jn][1]+bias);
      float v2=softplus_(acc[i][jn][2]+bias);
      float v3=softplus_(acc[i][jn][3]+bias);
      uint2 pk; pk.x=pk2(v0,v1); pk.y=pk2(v2,v3);
      *(uint2*)&dtT[((size_t)n*256+oc)*SEQL+mb]=pk; } }
}

// ---------------- k6bc: Bc/Cc = u @ xpw[8:10].T ----------------
__global__ __launch_bounds__(256) void k6bc(const unsigned short* __restrict__ uT,
  const float* __restrict__ xpw,float* __restrict__ Bc,float* __restrict__ Cc)
{
  int blk=blockIdx.x; int n=blk>>3; int t2=((blk&7)*256+threadIdx.x)*2;
  const unsigned short* ub=uT+(size_t)n*256*SEQL+t2;
  float sb0=0,sb1=0,sc0=0,sc1=0;
  for(int c=0;c<256;++c){
    unsigned int w_=*(const unsigned int*)&ub[(size_t)c*SEQL];
    float u0,u1; unp2(w_,u0,u1);
    float w8=xpw[8*256+c], w9=xpw[9*256+c];
    sb0+=u0*w8; sb1+=u1*w8; sc0+=u0*w9; sc1+=u1*w9;
  }
  size_t o=(size_t)n*SEQL+t2;
  *(float2*)&Bc[o]=make_float2(sb0,sb1);
  *(float2*)&Cc[o]=make_float2(sc0,sc1);
}

// ---------------- k7: chunked scan (8 chunks of 512) ----------------
__global__ __launch_bounds__(256) void k7p1(const unsigned short* __restrict__ uT,
  const unsigned short* __restrict__ dtT,const float* __restrict__ Bc,
  const float* __restrict__ A_log,float* __restrict__ Pq)
{
  int g=blockIdx.x*256+threadIdx.x;
  int ch=g&7, nc=g>>3, c=nc&255, n=nc>>8;
  float A=-__expf(A_log[c]);
  size_t base=(size_t)nc*SEQL+ch*512;
  const float* bp=Bc+(size_t)n*SEQL+ch*512;
  float P=1.f,q=0.f;
  for(int t0=0;t0<512;t0+=8){
    uint4 uu=*(const uint4*)&uT[base+t0];
    uint4 dd=*(const uint4*)&dtT[base+t0];
    float uv[8],dv[8];
    unp2(uu.x,uv[0],uv[1]);unp2(uu.y,uv[2],uv[3]);unp2(uu.z,uv[4],uv[5]);unp2(uu.w,uv[6],uv[7]);
    unp2(dd.x,dv[0],dv[1]);unp2(dd.y,dv[2],dv[3]);unp2(dd.z,dv[4],dv[5]);unp2(dd.w,dv[6],dv[7]);
    #pragma unroll
    for(int i=0;i<8;++i){
      float e=__expf(dv[i]*A);
      q=q*e+dv[i]*bp[t0+i]*uv[i];
      P*=e;
    }
  }
  Pq[(size_t)g*2]=P; Pq[(size_t)g*2+1]=q;
}

__global__ __launch_bounds__(256) void k7mid(const float* __restrict__ Pq,float* __restrict__ h0)
{
  int nc=blockIdx.x*256+threadIdx.x;
  float h=0.f;
  #pragma unroll
  for(int k=0;k<8;++k){
    h0[(size_t)nc*8+k]=h;
    h=h*Pq[((size_t)nc*8+k)*2]+Pq[((size_t)nc*8+k)*2+1];
  }
}

__global__ __launch_bounds__(256) void k7p2(unsigned short* __restrict__ uT,
  const unsigned short* __restrict__ dtT,const unsigned short* __restrict__ zT,
  const float* __restrict__ Bc,const float* __restrict__ Cc,
  const float* __restrict__ A_log,const float* __restrict__ Dp,
  const float* __restrict__ h0)
{
  int g=blockIdx.x*256+threadIdx.x;
  int ch=g&7, nc=g>>3, c=nc&255, n=nc>>8;
  float A=-__expf(A_log[c]), Dv=Dp[c];
  size_t base=(size_t)nc*SEQL+ch*512;
  const float* bp=Bc+(size_t)n*SEQL+ch*512;
  const float* cp=Cc+(size_t)n*SEQL+ch*512;
  float h=h0[g];
  for(int t0=0;t0<512;t0+=8){
    uint4 uu=*(const uint4*)&uT[base+t0];
    uint4 dd=*(const uint4*)&dtT[base+t0];
    uint4 zz=*(const uint4*)&zT[base+t0];
    float uv[8],dv[8],zv[8],yv[8];
    unp2(uu.x,uv[0],uv[1]);unp2(uu.y,uv[2],uv[3]);unp2(uu.z,uv[4],uv[5]);unp2(uu.w,uv[6],uv[7]);
    unp2(dd.x,dv[0],dv[1]);unp2(dd.y,dv[2],dv[3]);unp2(dd.z,dv[4],dv[5]);unp2(dd.w,dv[6],dv[7]);
    unp2(zz.x,zv[0],zv[1]);unp2(zz.y,zv[2],zv[3]);unp2(zz.z,zv[4],zv[5]);unp2(zz.w,zv[6],zv[7]);
    #pragma unroll
    for(int i=0;i<8;++i){
      float e=__expf(dv[i]*A);
      h=h*e+dv[i]*bp[t0+i]*uv[i];
      yv[i]=(h*cp[t0+i]+uv[i]*Dv)*zv[i];
    }
    uint4 oo; oo.x=pk2(yv[0],yv[1]); oo.y=pk2(yv[2],yv[3]); oo.z=pk2(yv[4],yv[5]); oo.w=pk2(yv[6],yv[7]);
    *(uint4*)&uT[base+t0]=oo;
  }
}

// ---------------- k8am: out_proj 256->128 -> Y4 [n][oc][t] bf16 (MFMA, transpose-staged A) ----------------
__global__ __launch_bounds__(256) void k8am(const unsigned short* __restrict__ yT,
  const float* __restrict__ Wout,unsigned short* __restrict__ Y4)
{
  MF_PRE();
  __shared__ __align__(16) short sA[64*72];
  __shared__ __align__(16) short sW[64*72];
  const int m0=blockIdx.x*64, n0=blockIdx.y*64, n=blockIdx.z;
  const unsigned short* ybase=yT+(size_t)n*256*SEQL;
  f32x4 acc[2][2]={};
  for(int k0=0;k0<256;k0+=64){
    { int c=k0+tk;
      STAGE_A_TR_BF(ybase+(size_t)c*SEQL+m0+tmb); }
    STAGE_W(Wout,256);
    __syncthreads();
    MF_STEP();
    __syncthreads();
  }
  #pragma unroll
  for(int jn=0;jn<2;++jn){ int oc=n0+wn*32+jn*16+fr;
    #pragma unroll
    for(int i=0;i<2;++i){ int mb=m0+wm*32+i*16+fg*4;
      uint2 pk; pk.x=pk2(acc[i][jn][0],acc[i][jn][1]); pk.y=pk2(acc[i][jn][2],acc[i][jn][3]);
      *(uint2*)&Y4[((size_t)n*128+oc)*SEQL+mb]=pk; } }
}

// ---------------- k8bm: pi GEMM + sigmoid gate + 4-dir sum -> ysum TOKEN-major [b][t][128] ----------------
__global__ __launch_bounds__(256) void k8bm(const float* __restrict__ Fp,const float* __restrict__ FpT,
  const unsigned short* __restrict__ Y4,const float* __restrict__ piw,const float* __restrict__ pib,
  float* __restrict__ ysum)
{
  MF_PRE();
  __shared__ __align__(16) short sA[64*72];
  __shared__ __align__(16) short sW[64*72];
  const int m0=blockIdx.x*64, n0=blockIdx.y*64, b=blockIdx.z;
  f32x4 gs[2][2]={};
  for(int d=0;d<4;++d){
    const int n=d*8+b;
    const float* src=((d<2)?Fp:FpT)+(size_t)b*PIX*128;
    const int rev=(d&1)?63:0;
    f32x4 acc[2][2]={};
    for(int k0=0;k0<256;k0+=64){
      if(k0<128){
        int t=m0+srow; int tm=(t&~63)|((t&63)^rev);
        const float* ap=src+(size_t)tm*128+k0+sch*16;
        STAGE_A_TOK(ap[j]);
      } else {
        int c=k0-128+tk;
        STAGE_A_TR_BF(Y4+((size_t)n*128+c)*SEQL+m0+tmb);
      }
      STAGE_W(piw,256);
      __syncthreads();
      MF_STEP();
      __syncthreads();
    }
    #pragma unroll
    for(int i=0;i<2;++i){
      #pragma unroll
      for(int jn=0;jn<2;++jn){
        int oc=n0+wn*32+jn*16+fr;
        int mb=m0+wm*32+i*16+fg*4;
        float pb=pib[oc];
        const unsigned short* yrow=Y4+((size_t)n*128+oc)*SEQL;
        #pragma unroll
        for(int p=0;p<4;++p){
          int t=mb+p; int tm=(t&~63)|((t&63)^rev);
          float pi=sigm(acc[i][jn][p]+pb);
          float x4=src[(size_t)tm*128+oc];
          float y4=b2f(yrow[t]);
          gs[i][jn][p]+=y4*pi+x4*(1.f-pi);
        }
      }
    }
  }
  #pragma unroll
  for(int i=0;i<2;++i)
    #pragma unroll
    for(int jn=0;jn<2;++jn){
      int oc=n0+wn*32+jn*16+fr;
      int mb=m0+wm*32+i*16+fg*4;
      #pragma unroll
      for(int p=0;p<4;++p)
        ysum[((size_t)b*PIX+mb+p)*128+oc]=gs[i][jn][p];
    }
}

// ---------------- k9m: final conv1x1 ((ysum+Fp) @ fw) (MFMA, token-major A) ----------------
__global__ __launch_bounds__(256) void k9m(const float* __restrict__ ysum,const float* __restrict__ Fp,
  const float* __restrict__ fw,float* __restrict__ out)
{
  MF_PRE();
  __shared__ __align__(16) short sA[64*72];
  __shared__ __align__(16) short sW[64*72];
  const int m0=blockIdx.x*64, n0=blockIdx.y*64, b=blockIdx.z;
  f32x4 acc[2][2]={};
  for(int k0=0;k0<128;k0+=64){
    { int t=m0+srow;
      const float* a1=ysum+((size_t)b*PIX+t)*128+k0+sch*16;
      const float* a2=Fp  +((size_t)b*PIX+t)*128+k0+sch*16;
      STAGE_A_TOK(a1[j]+a2[j]); }
    STAGE_W(fw,128);
    __syncthreads();
    MF_STEP();
    __syncthreads();
  }
  #pragma unroll
  for(int jn=0;jn<2;++jn){ int oc=n0+wn*32+jn*16+fr;
    #pragma unroll
    for(int i=0;i<2;++i){ int mb=m0+wm*32+i*16+fg*4;
      *(float4*)&out[((size_t)b*128+oc)*PIX+mb]=
        make_float4(acc[i][jn][0],acc[i][jn][1],acc[i][jn][2],acc[i][jn][3]); } }
}

extern "C" void kernel_launch(void* const* d_in,const int* in_sizes,int n_in,
  void* d_out,int out_size,void* d_ws,size_t ws_size,hipStream_t stream)
{
  (void)in_sizes; (void)n_in; (void)out_size; (void)ws_size;
  const float* FT1=(const float*)d_in[0];
  const float* FT2=(const float*)d_in[1];
  const float* gpw=(const float*)d_in[2];
  const float* g1g=(const float*)d_in[3];
  const float* g1b=(const float*)d_in[4];
  const float* g1m=(const float*)d_in[5];
  const float* g1v=(const float*)d_in[6];
  const float* gcw=(const float*)d_in[7];
  const float* g2g=(const float*)d_in[8];
  const float* g2b=(const float*)d_in[9];
  const float* g2m=(const float*)d_in[10];
  const float* g2v=(const float*)d_in[11];
  const float* sw1=(const float*)d_in[12];
  const float* sw2=(const float*)d_in[13];
  const float* prw=(const float*)d_in[14];
  const float* b3g=(const float*)d_in[15];
  const float* b3b=(const float*)d_in[16];
  const float* b3m=(const float*)d_in[17];
  const float* b3v=(const float*)d_in[18];
  const float* ipw=(const float*)d_in[19];
  const float* c1w=(const float*)d_in[20];
  const float* c1b=(const float*)d_in[21];
  const float* xpw=(const float*)d_in[22];
  const float* dtw=(const float*)d_in[23];
  const float* dtb=(const float*)d_in[24];
  const float* Alog=(const float*)d_in[25];
  const float* Dp=(const float*)d_in[26];
  const float* opw=(const float*)d_in[27];
  const float* piw=(const float*)d_in[28];
  const float* pib=(const float*)d_in[29];
  const float* fw=(const float*)d_in[30];

  char* w=(char*)d_ws;
  float* x1=(float*)(w);                                 // 64 MiB fp32
  float* x2=(float*)(w+(64ull<<20));                     // 64 MiB fp32
  unsigned short* uT=(unsigned short*)w;                 // aliases x1 (bf16, after k5)
  unsigned short* xsT=(unsigned short*)(w+(64ull<<20));  // aliases x2 (bf16, after k5)
  unsigned short* dtT=xsT;                               // aliases xsT (after k6b)
  unsigned short* Y4=xsT;                                // aliases dtT (after k7p2)
  unsigned short* zT=(unsigned short*)(w+(128ull<<20));  // 64 MiB bf16
  float* Fp=(float*)(w+(192ull<<20));                    // 16 MiB (token-major)
  float* FpT=(float*)(w+(208ull<<20));                   // 16 MiB (token-major)
  float* ysum=(float*)(w+(224ull<<20));                  // 16 MiB (token-major)
  float* Bc=(float*)(w+(240ull<<20));                    // 512 KiB
  float* Cc=Bc+32*4096;                                  // 512 KiB
  float* sr=Cc+32*4096;                                  // 32 KiB
  float* sse=sr+8192;                                    // 32 KiB
  float* Pq=sse+8192;                                    // 512 KiB
  float* h0=Pq+131072;                                   // 256 KiB
  float* Wc=h0+65536;                                    // 256 KiB

  kWc<<<256,256,0,stream>>>(dtw,xpw,Wc);
  k1m<<<dim3(64,8,8),256,0,stream>>>(FT1,FT2,gpw,g1g,g1b,g1m,g1v,x1);
  k2<<<16384,256,0,stream>>>(x1,gcw,g2g,g2b,g2m,g2v,x2);
  k3<<<8192,256,0,stream>>>(x1,x2,sr);
  k4<<<8,256,0,stream>>>(sr,sw1,sw2,sse);
  k5m<<<dim3(64,2,8),256,0,stream>>>(x1,x2,sse,prw,b3g,b3b,b3m,b3v,Fp,FpT);
  k6am<<<dim3(64,8,32),256,0,stream>>>(Fp,FpT,ipw,xsT,zT);
  k6b<<<16384,256,0,stream>>>(xsT,c1w,c1b,uT);
  k6cm<<<dim3(64,4,32),256,0,stream>>>(uT,Wc,dtb,dtT);
  k6bc<<<256,256,0,stream>>>(uT,xpw,Bc,Cc);
  k7p1<<<256,256,0,stream>>>(uT,dtT,Bc,Alog,Pq);
  k7mid<<<32,256,0,stream>>>(Pq,h0);
  k7p2<<<256,256,0,stream>>>(uT,dtT,zT,Bc,Cc,Alog,Dp,h0);
  k8am<<<dim3(64,2,32),256,0,stream>>>(uT,opw,Y4);
  k8bm<<<dim3(64,2,8),256,0,stream>>>(Fp,FpT,Y4,piw,pib,ysum);
  k9m<<<dim3(64,2,8),256,0,stream>>>(ysum,Fp,fw,(float*)d_out);
}

// Round 6
// 637.341 us; speedup vs baseline: 3.0444x; 1.3651x over previous
//
#include <hip/hip_runtime.h>
#include <hip/hip_bf16.h>

#define DEV static __device__ __forceinline__

#define PIX 4096
#define SEQL 4096
#define BEPS 1e-5f

DEV float b2f(unsigned short u){ unsigned int i=((unsigned int)u)<<16; float f; __builtin_memcpy(&f,&i,4); return f; }
DEV unsigned short f2b(float f){ __hip_bfloat16 h=__float2bfloat16(f); unsigned short s; __builtin_memcpy(&s,&h,2); return s; }
DEV short f2bs(float f){ return (short)f2b(f); }
DEV void unp2(unsigned int w, float&a, float&b){ unsigned int lo=w<<16, hi=w&0xffff0000u; __builtin_memcpy(&a,&lo,4); __builtin_memcpy(&b,&hi,4); }
DEV unsigned int pk2(float a,float b){ return (unsigned int)f2b(a)|((unsigned int)f2b(b)<<16); }
DEV float sigm(float x){ return 1.f/(1.f+__expf(-x)); }
DEV float silu_(float x){ return x*sigm(x); }
DEV float softplus_(float x){ return (x>20.f)?x:log1pf(__expf(x)); }

using short8 = __attribute__((ext_vector_type(8))) short;
using f32x4  = __attribute__((ext_vector_type(4))) float;
#define MFMA16 __builtin_amdgcn_mfma_f32_16x16x32_bf16

// ================= MFMA GEMM skeleton =================
// tile 64(M) x 64(N) x 64(K), 256 threads = 4 waves (2x2), 2x2 16x16x32 frags/wave.
// sA/sW: [row][k] (72 shorts/row), chunk-XOR swizzle:
//   element (r,k) at r*72 + (((k>>4)^(r&3))<<4) + (k&15)
// All MFMA operand reads are ds_read_b128; staging is pure uint4 copies where sources are bf16.

#define MF_PRE() \
  const int tid=threadIdx.x; \
  const int lane=tid&63, wid=tid>>6; \
  const int wm=wid&1, wn=wid>>1; \
  const int fr=lane&15, fg=lane>>4; \
  const int srow=tid>>2, sch=tid&3; \
  const int tk=tid&63, tmb=(tid>>6)*16;

// stage A row srow (token) from token-major bf16: 16 contiguous k
#define STAGE_A_TOK_BF(PTR) { \
  const unsigned short* ap_=(PTR); \
  uint4 q0_=*(const uint4*)ap_, q1_=*(const uint4*)(ap_+8); \
  int base_=srow*72+((sch^(srow&3))*16); \
  *(uint4*)&sA[base_]=q0_; *(uint4*)&sA[base_+8]=q1_; }

// stage A row srow = sum of two token-major bf16 sources
#define STAGE_A_SUM_BF(P1,P2) { \
  const unsigned short* p1_=(P1); const unsigned short* p2_=(P2); \
  unsigned short h1[16],h2[16]; \
  *(uint4*)&h1[0]=*(const uint4*)p1_; *(uint4*)&h1[8]=*(const uint4*)(p1_+8); \
  *(uint4*)&h2[0]=*(const uint4*)p2_; *(uint4*)&h2[8]=*(const uint4*)(p2_+8); \
  union { short h[16]; uint4 q[2]; } tmpa; \
  _Pragma("unroll") for(int j=0;j<16;++j) tmpa.h[j]=f2bs(b2f(h1[j])+b2f(h2[j])); \
  int base_=srow*72+((sch^(srow&3))*16); \
  *(uint4*)&sA[base_]=tmpa.q[0]; *(uint4*)&sA[base_+8]=tmpa.q[1]; }

// transpose-stage from channel-major fp32 (k1m only): thread owns channel tk, 16 m at tmb
#define STAGE_A_TR_F32(EXPR16) { \
  float tv[16]; \
  _Pragma("unroll") for(int j=0;j<16;++j) tv[j]=(EXPR16); \
  _Pragma("unroll") for(int j=0;j<16;++j){ int m_=tmb+j; \
    sA[m_*72+(((tk>>4)^(m_&3))<<4)+(tk&15)]=f2bs(tv[j]); } }

// transpose-stage from channel-major bf16 (k5m): raw ushort moves, no cvt
#define STAGE_A_TR_BF16(PTR) { \
  const unsigned short* ap_=(PTR); \
  unsigned short hv[16]; \
  *(uint4*)&hv[0]=*(const uint4*)ap_; *(uint4*)&hv[8]=*(const uint4*)(ap_+8); \
  _Pragma("unroll") for(int j=0;j<16;++j){ int m_=tmb+j; \
    sA[m_*72+(((tk>>4)^(m_&3))<<4)+(tk&15)]=(short)hv[j]; } }

// stage W from pre-converted bf16 weights [n][k]
#define STAGE_W_BF(PTR,LDK) { \
  const unsigned short* wp_=(PTR)+(size_t)(n0+srow)*(LDK)+k0+sch*16; \
  uint4 q0_=*(const uint4*)wp_, q1_=*(const uint4*)(wp_+8); \
  int sw_=((sch^(srow&3))*16); \
  *(uint4*)&sW[srow*72+sw_]=q0_; *(uint4*)&sW[srow*72+sw_+8]=q1_; }

#define MF_STEP() \
  _Pragma("unroll") \
  for(int kk=0;kk<64;kk+=32){ \
    short8 af[2],bfv[2]; const int kq_=kk+fg*8; \
    _Pragma("unroll") for(int i=0;i<2;++i){ int ml=wm*32+i*16+fr; \
      af[i]=*(const short8*)&sA[ml*72+(((kq_>>4)^(ml&3))<<4)+(kq_&15)]; } \
    _Pragma("unroll") for(int jn=0;jn<2;++jn){ int nl=wn*32+jn*16+fr; \
      bfv[jn]=*(const short8*)&sW[nl*72+(((kq_>>4)^(nl&3))<<4)+(kq_&15)]; } \
    _Pragma("unroll") for(int i=0;i<2;++i) \
      _Pragma("unroll") for(int jn=0;jn<2;++jn) \
        acc[i][jn]=MFMA16(af[i],bfv[jn],acc[i][jn],0,0,0); }

// ---------------- weight prep ----------------
__global__ __launch_bounds__(256) void kWb(const float* __restrict__ g,const float* __restrict__ ip,
  const float* __restrict__ op,const float* __restrict__ pw,const float* __restrict__ f,
  unsigned short* __restrict__ gb,unsigned short* __restrict__ ib,unsigned short* __restrict__ ob,
  unsigned short* __restrict__ pb,unsigned short* __restrict__ fb)
{
  int x=blockIdx.x*256+threadIdx.x;
  if(x<131072) gb[x]=f2b(g[x]);
  if(x<65536)  ib[x]=f2b(ip[x]);
  if(x<32768){ ob[x]=f2b(op[x]); pb[x]=f2b(pw[x]); }
  if(x<16384)  fb[x]=f2b(f[x]);
}

__global__ __launch_bounds__(256) void kWc(const float* __restrict__ dtw,const float* __restrict__ xpw,
  unsigned short* __restrict__ Wcb)
{
  int c=blockIdx.x, k=threadIdx.x;
  float a=0.f;
  #pragma unroll
  for(int i=0;i<8;++i) a+=dtw[c*8+i]*xpw[i*256+k];
  Wcb[c*256+k]=f2b(a);
}

// Wsb[b][oc][c] = prw[oc][c]*sse[b][c]  (SE scale folded into proj weights, per batch)
__global__ __launch_bounds__(256) void kWse(const float* __restrict__ prw,const float* __restrict__ sse,
  unsigned short* __restrict__ Wsb)
{
  int idx=blockIdx.x*256+threadIdx.x;        // 8*131072
  int b=idx>>17, r=idx&131071, oc=r>>10, c=r&1023;
  Wsb[idx]=f2b(prw[(size_t)oc*1024+c]*sse[b*1024+c]);
}

// ---------------- k1m: conv1x1 256->512 + BN + ReLU -> x1 bf16 [b][c][t] ----------------
__global__ __launch_bounds__(256) void k1m(const float* __restrict__ FT1,const float* __restrict__ FT2,
  const unsigned short* __restrict__ Wpb,const float* __restrict__ gg,const float* __restrict__ gb,
  const float* __restrict__ gm,const float* __restrict__ gv,unsigned short* __restrict__ x1)
{
  MF_PRE();
  __shared__ __align__(16) short sA[64*72];
  __shared__ __align__(16) short sW[64*72];
  const int m0=blockIdx.x*64, n0=blockIdx.y*64, b=blockIdx.z;
  f32x4 acc[2][2]={};
  for(int k0=0;k0<256;k0+=64){
    { int c=k0+tk;
      const float* s_=(c<128)? FT1+((size_t)b*128+c)*PIX : FT2+((size_t)b*128+c-128)*PIX;
      const float* ap=s_+m0+tmb;
      STAGE_A_TR_F32(ap[j]); }
    STAGE_W_BF(Wpb,256);
    __syncthreads();
    MF_STEP();
    __syncthreads();
  }
  #pragma unroll
  for(int jn=0;jn<2;++jn){ int oc=n0+wn*32+jn*16+fr;
    float ks=gg[oc]*rsqrtf(gv[oc]+BEPS), kb=gb[oc]-gm[oc]*ks;
    #pragma unroll
    for(int i=0;i<2;++i){ int mb=m0+wm*32+i*16+fg*4;
      float v0=fmaxf(acc[i][jn][0]*ks+kb,0.f), v1=fmaxf(acc[i][jn][1]*ks+kb,0.f);
      float v2=fmaxf(acc[i][jn][2]*ks+kb,0.f), v3=fmaxf(acc[i][jn][3]*ks+kb,0.f);
      uint2 pk; pk.x=pk2(v0,v1); pk.y=pk2(v2,v3);
      *(uint2*)&x1[((size_t)b*512+oc)*PIX+mb]=pk; } }
}

// ---------------- k2: depthwise 3x3 + BN + ReLU (bf16 in/out, channel-major) ----------------
__global__ __launch_bounds__(256) void k2(const unsigned short* __restrict__ x1,const float* __restrict__ cw,
  const float* __restrict__ gg,const float* __restrict__ gb,const float* __restrict__ gm,
  const float* __restrict__ gv,unsigned short* __restrict__ x2)
{
  int gid=blockIdx.x*256+threadIdx.x;
  int wq=gid&15, h=(gid>>4)&63, bc=gid>>10;
  int c=bc&511;
  const unsigned short* src=x1+(size_t)bc*PIX;
  float wv[9];
  #pragma unroll
  for(int i=0;i<9;++i) wv[i]=cw[c*9+i];
  float ks=gg[c]*rsqrtf(gv[c]+BEPS), kb=gb[c]-gm[c]*ks;
  int wb=wq*4;
  float o[4]={};
  #pragma unroll
  for(int dh=0;dh<3;++dh){ int hh=h+dh-1; if(hh<0||hh>63) continue;
    const unsigned short* row=src+hh*64;
    float rv[6];
    #pragma unroll
    for(int j=0;j<6;++j){ int wc=wb-1+j; rv[j]=(wc>=0&&wc<64)?b2f(row[wc]):0.f; }
    #pragma unroll
    for(int dw=0;dw<3;++dw){ float wgt=wv[dh*3+dw];
      #pragma unroll
      for(int i=0;i<4;++i) o[i]+=rv[i+dw]*wgt; } }
  float v0=fmaxf(o[0]*ks+kb,0.f), v1=fmaxf(o[1]*ks+kb,0.f);
  float v2=fmaxf(o[2]*ks+kb,0.f), v3=fmaxf(o[3]*ks+kb,0.f);
  uint2 pk; pk.x=pk2(v0,v1); pk.y=pk2(v2,v3);
  *(uint2*)&x2[(size_t)bc*PIX+h*64+wb]=pk;
}

// ---------------- k3: SE mean (bf16 in) ----------------
__global__ __launch_bounds__(256) void k3(const unsigned short* __restrict__ x1,
  const unsigned short* __restrict__ x2,float* __restrict__ sr)
{
  int bc=blockIdx.x; int cg=bc&1023, b=bc>>10;
  const unsigned short* src=(cg<512)? x1+((size_t)b*512+cg)*PIX : x2+((size_t)b*512+cg-512)*PIX;
  float s=0;
  for(int i=threadIdx.x;i<512;i+=256){
    uint4 v=((const uint4*)src)[i];
    float a0,a1; unp2(v.x,a0,a1); s+=a0+a1;
    unp2(v.y,a0,a1); s+=a0+a1;
    unp2(v.z,a0,a1); s+=a0+a1;
    unp2(v.w,a0,a1); s+=a0+a1;
  }
  #pragma unroll
  for(int off=32;off;off>>=1) s+=__shfl_down(s,off);
  __shared__ float red[4];
  if((threadIdx.x&63)==0) red[threadIdx.x>>6]=s;
  __syncthreads();
  if(threadIdx.x==0) sr[bc]=(red[0]+red[1]+red[2]+red[3])*(1.f/4096.f);
}

// ---------------- k4: SE MLP ----------------
__global__ __launch_bounds__(256) void k4(const float* __restrict__ sr,const float* __restrict__ w1,
  const float* __restrict__ w2,float* __restrict__ sOut)
{
  int b=blockIdx.x;
  __shared__ float ls[1024];
  __shared__ float pm[4][64];
  __shared__ float mid[64];
  for(int i=threadIdx.x;i<1024;i+=256) ls[i]=sr[b*1024+i];
  __syncthreads();
  int k=threadIdx.x&63, part=threadIdx.x>>6;
  float p=0;
  for(int c=part*256;c<part*256+256;++c) p+=ls[c]*w1[k*1024+c];
  pm[part][k]=p;
  __syncthreads();
  if(threadIdx.x<64) mid[threadIdx.x]=fmaxf(pm[0][threadIdx.x]+pm[1][threadIdx.x]+pm[2][threadIdx.x]+pm[3][threadIdx.x],0.f);
  __syncthreads();
  for(int j=threadIdx.x;j<1024;j+=256){
    float a=0;
    for(int kk=0;kk<64;++kk) a+=mid[kk]*w2[j*64+kk];
    sOut[b*1024+j]=sigm(a);
  }
}

// ---------------- k5m: proj 1024->128 (SE folded in Wsb) + BN3 -> Fp, FpT bf16 [b][t][128] ----------------
__global__ __launch_bounds__(256) void k5m(const unsigned short* __restrict__ x1,
  const unsigned short* __restrict__ x2,const unsigned short* __restrict__ Wsb,
  const float* __restrict__ g3,const float* __restrict__ b3,const float* __restrict__ m3,
  const float* __restrict__ v3,unsigned short* __restrict__ Fp,unsigned short* __restrict__ FpT)
{
  MF_PRE();
  __shared__ __align__(16) short sA[64*72];
  __shared__ __align__(16) short sW[64*72];
  const int m0=blockIdx.x*64, n0=blockIdx.y*64, b=blockIdx.z;
  const unsigned short* Wb=Wsb+(size_t)b*131072;
  f32x4 acc[2][2]={};
  for(int k0=0;k0<1024;k0+=64){
    { int c=k0+tk;
      const unsigned short* s_=(c<512)? x1+((size_t)b*512+c)*PIX : x2+((size_t)b*512+c-512)*PIX;
      STAGE_A_TR_BF16(s_+m0+tmb); }
    STAGE_W_BF(Wb,1024);
    __syncthreads();
    MF_STEP();
    __syncthreads();
  }
  #pragma unroll
  for(int jn=0;jn<2;++jn){ int oc=n0+wn*32+jn*16+fr;
    float ks=g3[oc]*rsqrtf(v3[oc]+BEPS), kb=b3[oc]-m3[oc]*ks;
    #pragma unroll
    for(int i=0;i<2;++i){ int mb=m0+wm*32+i*16+fg*4;
      #pragma unroll
      for(int p=0;p<4;++p){ int pp=mb+p; unsigned short val=f2b(acc[i][jn][p]*ks+kb);
        Fp[((size_t)b*PIX+pp)*128+oc]=val;
        int q=((pp&63)<<6)|(pp>>6);
        FpT[((size_t)b*PIX+q)*128+oc]=val; } } }
}

// ---------------- k6am: in_proj 128->512 -> xsT, zT bf16 [n][t][256] ----------------
__global__ __launch_bounds__(256) void k6am(const unsigned short* __restrict__ Fp,
  const unsigned short* __restrict__ FpT,const unsigned short* __restrict__ Winb,
  unsigned short* __restrict__ xsT,unsigned short* __restrict__ zT)
{
  MF_PRE();
  __shared__ __align__(16) short sA[64*72];
  __shared__ __align__(16) short sW[64*72];
  const int m0=blockIdx.x*64, n0=blockIdx.y*64, n=blockIdx.z;
  const int d=n>>3, b=n&7;
  const unsigned short* src=((d<2)?Fp:FpT)+(size_t)b*PIX*128;
  const int rev=(d&1)?63:0;
  f32x4 acc[2][2]={};
  for(int k0=0;k0<128;k0+=64){
    { int t=m0+srow; int tm=(t&~63)|((t&63)^rev);
      STAGE_A_TOK_BF(src+(size_t)tm*128+k0+sch*16); }
    STAGE_W_BF(Winb,128);
    __syncthreads();
    MF_STEP();
    __syncthreads();
  }
  #pragma unroll
  for(int jn=0;jn<2;++jn){ int r=n0+wn*32+jn*16+fr;
    unsigned short* dst; int row; bool dosilu;
    if(r<256){ dst=xsT; row=r; dosilu=false; } else { dst=zT; row=r-256; dosilu=true; }
    #pragma unroll
    for(int i=0;i<2;++i){ int mb=m0+wm*32+i*16+fg*4;
      #pragma unroll
      for(int p=0;p<4;++p){ float v=acc[i][jn][p]; if(dosilu) v=silu_(v);
        dst[((size_t)n*SEQL+mb+p)*256+row]=f2b(v); } } }
}

// ---------------- k6b: causal conv1d (k=4) + SiLU (token-major) ----------------
__global__ __launch_bounds__(256) void k6b(const unsigned short* __restrict__ xsT,
  const float* __restrict__ cw,const float* __restrict__ cb,unsigned short* __restrict__ uT)
{
  int gid=blockIdx.x*256+threadIdx.x;
  int cb8=gid&31, tb=(gid>>5)&511, n=gid>>14;
  int c0=cb8*8, t0=tb*8;
  const unsigned short* base=xsT+(size_t)n*SEQL*256+c0;
  float w0[8],w1[8],w2[8],w3[8],bb[8];
  #pragma unroll
  for(int j=0;j<8;++j){ float4 wv=*(const float4*)&cw[(c0+j)*4];
    w0[j]=wv.x; w1[j]=wv.y; w2[j]=wv.z; w3[j]=wv.w; bb[j]=cb[c0+j]; }
  float ra[8],rb[8],rc[8],rd[8];
  #pragma unroll
  for(int j=0;j<8;++j){ ra[j]=0.f; rb[j]=0.f; rc[j]=0.f; }
  if(t0>=3){
    uint4 v;
    v=*(const uint4*)(base+(size_t)(t0-3)*256); unp2(v.x,ra[0],ra[1]);unp2(v.y,ra[2],ra[3]);unp2(v.z,ra[4],ra[5]);unp2(v.w,ra[6],ra[7]);
    v=*(const uint4*)(base+(size_t)(t0-2)*256); unp2(v.x,rb[0],rb[1]);unp2(v.y,rb[2],rb[3]);unp2(v.z,rb[4],rb[5]);unp2(v.w,rb[6],rb[7]);
    v=*(const uint4*)(base+(size_t)(t0-1)*256); unp2(v.x,rc[0],rc[1]);unp2(v.y,rc[2],rc[3]);unp2(v.z,rc[4],rc[5]);unp2(v.w,rc[6],rc[7]);
  }
  unsigned short* ob=uT+(size_t)n*SEQL*256+c0;
  for(int j=0;j<8;++j){
    uint4 v=*(const uint4*)(base+(size_t)(t0+j)*256);
    unp2(v.x,rd[0],rd[1]);unp2(v.y,rd[2],rd[3]);unp2(v.z,rd[4],rd[5]);unp2(v.w,rd[6],rd[7]);
    float o[8];
    #pragma unroll
    for(int q=0;q<8;++q){
      o[q]=silu_(ra[q]*w0[q]+rb[q]*w1[q]+rc[q]*w2[q]+rd[q]*w3[q]+bb[q]);
      ra[q]=rb[q]; rb[q]=rc[q]; rc[q]=rd[q];
    }
    uint4 ov; ov.x=pk2(o[0],o[1]); ov.y=pk2(o[2],o[3]); ov.z=pk2(o[4],o[5]); ov.w=pk2(o[6],o[7]);
    *(uint4*)(ob+(size_t)(t0+j)*256)=ov;
  }
}

// ---------------- k6cm: dt GEMM (u @ Wc.T) + bias + softplus -> dtT bf16 [n][t][256] ----------------
__global__ __launch_bounds__(256) void k6cm(const unsigned short* __restrict__ uT,
  const unsigned short* __restrict__ Wcb,const float* __restrict__ dtb,
  unsigned short* __restrict__ dtT)
{
  MF_PRE();
  __shared__ __align__(16) short sA[64*72];
  __shared__ __align__(16) short sW[64*72];
  const int m0=blockIdx.x*64, n0=blockIdx.y*64, n=blockIdx.z;
  const unsigned short* ubase=uT+(size_t)n*SEQL*256;
  f32x4 acc[2][2]={};
  for(int k0=0;k0<256;k0+=64){
    STAGE_A_TOK_BF(ubase+(size_t)(m0+srow)*256+k0+sch*16);
    STAGE_W_BF(Wcb,256);
    __syncthreads();
    MF_STEP();
    __syncthreads();
  }
  #pragma unroll
  for(int jn=0;jn<2;++jn){ int oc=n0+wn*32+jn*16+fr;
    float bias=dtb[oc];
    #pragma unroll
    for(int i=0;i<2;++i){ int mb=m0+wm*32+i*16+fg*4;
      #pragma unroll
      for(int p=0;p<4;++p)
        dtT[((size_t)n*SEQL+mb+p)*256+oc]=f2b(softplus_(acc[i][jn][p]+bias)); } }
}

// ---------------- k6bc: Bc/Cc = u @ xpw[8:10].T (wave per token) ----------------
__global__ __launch_bounds__(256) void k6bc(const unsigned short* __restrict__ uT,
  const float* __restrict__ xpw,float* __restrict__ Bc,float* __restrict__ Cc)
{
  int inst=blockIdx.x*4+(threadIdx.x>>6);
  int ln=threadIdx.x&63;
  int n=inst>>12, t=inst&4095;
  const unsigned short* up=uT+((size_t)n*SEQL+t)*256+ln*4;
  uint2 uu=*(const uint2*)up;
  float u0,u1,u2,u3; unp2(uu.x,u0,u1); unp2(uu.y,u2,u3);
  float4 w8=*(const float4*)&xpw[8*256+ln*4];
  float4 w9=*(const float4*)&xpw[9*256+ln*4];
  float sb=u0*w8.x+u1*w8.y+u2*w8.z+u3*w8.w;
  float sc=u0*w9.x+u1*w9.y+u2*w9.z+u3*w9.w;
  #pragma unroll
  for(int off=32;off;off>>=1){ sb+=__shfl_xor(sb,off); sc+=__shfl_xor(sc,off); }
  if(ln==0){ Bc[(size_t)n*SEQL+t]=sb; Cc[(size_t)n*SEQL+t]=sc; }
}

// ---------------- k7: chunked scan, 32 chunks of 128, 4 channels/lane ----------------
__global__ __launch_bounds__(256) void k7p1(const unsigned short* __restrict__ uT,
  const unsigned short* __restrict__ dtT,const float* __restrict__ Bc,
  const float* __restrict__ A_log,float* __restrict__ Pq)
{
  int g=blockIdx.x*256+threadIdx.x;        // 65536
  int cq=g&63, ch=(g>>6)&31, n=g>>11;
  int c0=cq*4;
  float A0=-__expf(A_log[c0]),A1=-__expf(A_log[c0+1]),A2=-__expf(A_log[c0+2]),A3=-__expf(A_log[c0+3]);
  size_t tbase=((size_t)n*SEQL+ch*128)*256+c0;
  const float* bp=Bc+(size_t)n*SEQL+ch*128;
  float P0=1,P1=1,P2=1,P3=1,q0=0,q1=0,q2=0,q3=0;
  for(int t=0;t<128;++t){
    uint2 uu=*(const uint2*)&uT[tbase+(size_t)t*256];
    uint2 dd=*(const uint2*)&dtT[tbase+(size_t)t*256];
    float u0,u1,u2,u3,d0,d1,d2,d3;
    unp2(uu.x,u0,u1); unp2(uu.y,u2,u3);
    unp2(dd.x,d0,d1); unp2(dd.y,d2,d3);
    float bv=bp[t];
    float e0=__expf(d0*A0),e1=__expf(d1*A1),e2=__expf(d2*A2),e3=__expf(d3*A3);
    q0=q0*e0+d0*bv*u0; q1=q1*e1+d1*bv*u1; q2=q2*e2+d2*bv*u2; q3=q3*e3+d3*bv*u3;
    P0*=e0; P1*=e1; P2*=e2; P3*=e3;
  }
  size_t o=(((size_t)n*256+c0)*32+ch)*2;
  Pq[o]=P0; Pq[o+1]=q0; Pq[o+64]=P1; Pq[o+65]=q1;
  Pq[o+128]=P2; Pq[o+129]=q2; Pq[o+192]=P3; Pq[o+193]=q3;
}

__global__ __launch_bounds__(256) void k7mid(const float* __restrict__ Pq,float* __restrict__ h0)
{
  int nc=blockIdx.x*256+threadIdx.x;       // 8192
  float h=0.f;
  for(int ch=0;ch<32;++ch){
    h0[(size_t)nc*32+ch]=h;
    h=h*Pq[((size_t)nc*32+ch)*2]+Pq[((size_t)nc*32+ch)*2+1];
  }
}

__global__ __launch_bounds__(256) void k7p2(unsigned short* __restrict__ uT,
  const unsigned short* __restrict__ dtT,const unsigned short* __restrict__ zT,
  const float* __restrict__ Bc,const float* __restrict__ Cc,
  const float* __restrict__ A_log,const float* __restrict__ Dp,
  const float* __restrict__ h0)
{
  int g=blockIdx.x*256+threadIdx.x;
  int cq=g&63, ch=(g>>6)&31, n=g>>11;
  int c0=cq*4;
  float A0=-__expf(A_log[c0]),A1=-__expf(A_log[c0+1]),A2=-__expf(A_log[c0+2]),A3=-__expf(A_log[c0+3]);
  float D0=Dp[c0],D1=Dp[c0+1],D2=Dp[c0+2],D3=Dp[c0+3];
  size_t tbase=((size_t)n*SEQL+ch*128)*256+c0;
  const float* bp=Bc+(size_t)n*SEQL+ch*128;
  const float* cp=Cc+(size_t)n*SEQL+ch*128;
  size_t hb=((size_t)n*256+c0)*32+ch;
  float h0v=h0[hb],h1v=h0[hb+32],h2v=h0[hb+64],h3v=h0[hb+96];
  for(int t=0;t<128;++t){
    uint2 uu=*(const uint2*)&uT[tbase+(size_t)t*256];
    uint2 dd=*(const uint2*)&dtT[tbase+(size_t)t*256];
    uint2 zz=*(const uint2*)&zT[tbase+(size_t)t*256];
    float u0,u1,u2,u3,d0,d1,d2,d3,z0,z1,z2,z3;
    unp2(uu.x,u0,u1); unp2(uu.y,u2,u3);
    unp2(dd.x,d0,d1); unp2(dd.y,d2,d3);
    unp2(zz.x,z0,z1); unp2(zz.y,z2,z3);
    float bv=bp[t], cv=cp[t];
    float e0=__expf(d0*A0),e1=__expf(d1*A1),e2=__expf(d2*A2),e3=__expf(d3*A3);
    h0v=h0v*e0+d0*bv*u0; h1v=h1v*e1+d1*bv*u1; h2v=h2v*e2+d2*bv*u2; h3v=h3v*e3+d3*bv*u3;
    float y0=(h0v*cv+u0*D0)*z0, y1=(h1v*cv+u1*D1)*z1;
    float y2=(h2v*cv+u2*D2)*z2, y3=(h3v*cv+u3*D3)*z3;
    uint2 oo; oo.x=pk2(y0,y1); oo.y=pk2(y2,y3);
    *(uint2*)&uT[tbase+(size_t)t*256]=oo;
  }
}

// ---------------- k8am: out_proj 256->128 -> Y4 bf16 [n][t][128] ----------------
__global__ __launch_bounds__(256) void k8am(const unsigned short* __restrict__ yT,
  const unsigned short* __restrict__ Woutb,unsigned short* __restrict__ Y4)
{
  MF_PRE();
  __shared__ __align__(16) short sA[64*72];
  __shared__ __align__(16) short sW[64*72];
  const int m0=blockIdx.x*64, n0=blockIdx.y*64, n=blockIdx.z;
  const unsigned short* ybase=yT+(size_t)n*SEQL*256;
  f32x4 acc[2][2]={};
  for(int k0=0;k0<256;k0+=64){
    STAGE_A_TOK_BF(ybase+(size_t)(m0+srow)*256+k0+sch*16);
    STAGE_W_BF(Woutb,256);
    __syncthreads();
    MF_STEP();
    __syncthreads();
  }
  #pragma unroll
  for(int jn=0;jn<2;++jn){ int oc=n0+wn*32+jn*16+fr;
    #pragma unroll
    for(int i=0;i<2;++i){ int mb=m0+wm*32+i*16+fg*4;
      #pragma unroll
      for(int p=0;p<4;++p)
        Y4[((size_t)n*SEQL+mb+p)*128+oc]=f2b(acc[i][jn][p]); } }
}

// ---------------- k8bm: pi GEMM + sigmoid gate + 4-dir sum -> ysum bf16 [b][t][128] ----------------
__global__ __launch_bounds__(256) void k8bm(const unsigned short* __restrict__ Fp,
  const unsigned short* __restrict__ FpT,const unsigned short* __restrict__ Y4,
  const unsigned short* __restrict__ piwb,const float* __restrict__ pib,
  unsigned short* __restrict__ ysum)
{
  MF_PRE();
  __shared__ __align__(16) short sA[64*72];
  __shared__ __align__(16) short sW[64*72];
  const int m0=blockIdx.x*64, n0=blockIdx.y*64, b=blockIdx.z;
  f32x4 gs[2][2]={};
  for(int d=0;d<4;++d){
    const int n=d*8+b;
    const unsigned short* src=((d<2)?Fp:FpT)+(size_t)b*PIX*128;
    const int rev=(d&1)?63:0;
    f32x4 acc[2][2]={};
    for(int k0=0;k0<256;k0+=64){
      if(k0<128){
        int t=m0+srow; int tm=(t&~63)|((t&63)^rev);
        STAGE_A_TOK_BF(src+(size_t)tm*128+k0+sch*16);
      } else {
        STAGE_A_TOK_BF(Y4+((size_t)n*SEQL+m0+srow)*128+(k0-128)+sch*16);
      }
      STAGE_W_BF(piwb,256);
      __syncthreads();
      MF_STEP();
      __syncthreads();
    }
    #pragma unroll
    for(int i=0;i<2;++i){
      #pragma unroll
      for(int jn=0;jn<2;++jn){
        int oc=n0+wn*32+jn*16+fr;
        int mb=m0+wm*32+i*16+fg*4;
        float pb=pib[oc];
        #pragma unroll
        for(int p=0;p<4;++p){
          int t=mb+p; int tm=(t&~63)|((t&63)^rev);
          float pi=sigm(acc[i][jn][p]+pb);
          float x4=b2f(src[(size_t)tm*128+oc]);
          float y4=b2f(Y4[((size_t)n*SEQL+t)*128+oc]);
          gs[i][jn][p]+=y4*pi+x4*(1.f-pi);
        }
      }
    }
  }
  #pragma unroll
  for(int i=0;i<2;++i)
    #pragma unroll
    for(int jn=0;jn<2;++jn){
      int oc=n0+wn*32+jn*16+fr;
      int mb=m0+wm*32+i*16+fg*4;
      #pragma unroll
      for(int p=0;p<4;++p)
        ysum[((size_t)b*PIX+mb+p)*128+oc]=f2b(gs[i][jn][p]);
    }
}

// ---------------- k9m: final conv1x1 ((ysum+Fp) @ fw) -> out fp32 [b][c][t] ----------------
__global__ __launch_bounds__(256) void k9m(const unsigned short* __restrict__ ysum,
  const unsigned short* __restrict__ Fp,const unsigned short* __restrict__ fwb,
  float* __restrict__ out)
{
  MF_PRE();
  __shared__ __align__(16) short sA[64*72];
  __shared__ __align__(16) short sW[64*72];
  const int m0=blockIdx.x*64, n0=blockIdx.y*64, b=blockIdx.z;
  f32x4 acc[2][2]={};
  for(int k0=0;k0<128;k0+=64){
    { size_t off=((size_t)b*PIX+m0+srow)*128+k0+sch*16;
      STAGE_A_SUM_BF(ysum+off,Fp+off); }
    STAGE_W_BF(fwb,128);
    __syncthreads();
    MF_STEP();
    __syncthreads();
  }
  #pragma unroll
  for(int jn=0;jn<2;++jn){ int oc=n0+wn*32+jn*16+fr;
    #pragma unroll
    for(int i=0;i<2;++i){ int mb=m0+wm*32+i*16+fg*4;
      *(float4*)&out[((size_t)b*128+oc)*PIX+mb]=
        make_float4(acc[i][jn][0],acc[i][jn][1],acc[i][jn][2],acc[i][jn][3]); } }
}

extern "C" void kernel_launch(void* const* d_in,const int* in_sizes,int n_in,
  void* d_out,int out_size,void* d_ws,size_t ws_size,hipStream_t stream)
{
  (void)in_sizes; (void)n_in; (void)out_size; (void)ws_size;
  const float* FT1=(const float*)d_in[0];
  const float* FT2=(const float*)d_in[1];
  const float* gpw=(const float*)d_in[2];
  const float* g1g=(const float*)d_in[3];
  const float* g1b=(const float*)d_in[4];
  const float* g1m=(const float*)d_in[5];
  const float* g1v=(const float*)d_in[6];
  const float* gcw=(const float*)d_in[7];
  const float* g2g=(const float*)d_in[8];
  const float* g2b=(const float*)d_in[9];
  const float* g2m=(const float*)d_in[10];
  const float* g2v=(const float*)d_in[11];
  const float* sw1=(const float*)d_in[12];
  const float* sw2=(const float*)d_in[13];
  const float* prw=(const float*)d_in[14];
  const float* b3g=(const float*)d_in[15];
  const float* b3b=(const float*)d_in[16];
  const float* b3m=(const float*)d_in[17];
  const float* b3v=(const float*)d_in[18];
  const float* ipw=(const float*)d_in[19];
  const float* c1w=(const float*)d_in[20];
  const float* c1b=(const float*)d_in[21];
  const float* xpw=(const float*)d_in[22];
  const float* dtw=(const float*)d_in[23];
  const float* dtb=(const float*)d_in[24];
  const float* Alog=(const float*)d_in[25];
  const float* Dp=(const float*)d_in[26];
  const float* opw=(const float*)d_in[27];
  const float* piw=(const float*)d_in[28];
  const float* pib=(const float*)d_in[29];
  const float* fw=(const float*)d_in[30];

  char* w=(char*)d_ws;
  const size_t MB=1ull<<20;
  unsigned short* x1b =(unsigned short*)(w);            // 32MB bf16 [b][c][t]
  unsigned short* x2b =(unsigned short*)(w+32*MB);      // 32MB
  unsigned short* uT  =(unsigned short*)(w);            // 64MB [n][t][256] (after k5m; x1/x2 dead)
  unsigned short* xsT =(unsigned short*)(w+64*MB);      // 64MB [n][t][256]
  unsigned short* dtT =(unsigned short*)(w+64*MB);      // 64MB (after k6b; xsT dead)
  unsigned short* Y4  =(unsigned short*)(w+64*MB);      // 32MB (after k7p2; dtT dead)
  unsigned short* zT  =(unsigned short*)(w+128*MB);     // 64MB [n][t][256]
  unsigned short* Fpb =(unsigned short*)(w+192*MB);     // 8MB  [b][t][128]
  unsigned short* FpTb=(unsigned short*)(w+200*MB);     // 8MB
  unsigned short* ysb =(unsigned short*)(w+208*MB);     // 8MB
  float* Bc =(float*)(w+216*MB);                        // 512KB
  float* Cc =(float*)(w+216*MB+512*1024);               // 512KB
  float* sr =(float*)(w+217*MB);                        // 32KB
  float* sse=(float*)(w+217*MB+32*1024);                // 32KB
  float* Pq =(float*)(w+218*MB);                        // 2MB
  float* h0 =(float*)(w+220*MB);                        // 1MB
  unsigned short* Wcb =(unsigned short*)(w+221*MB);     // 128KB
  unsigned short* gpwb=(unsigned short*)(w+222*MB);     // 256KB
  unsigned short* ipwb=(unsigned short*)(w+223*MB);     // 128KB
  unsigned short* opwb=(unsigned short*)(w+224*MB);     // 64KB
  unsigned short* piwb=(unsigned short*)(w+224*MB+64*1024); // 64KB
  unsigned short* fwb =(unsigned short*)(w+224*MB+128*1024);// 32KB
  unsigned short* Wsb =(unsigned short*)(w+225*MB);     // 2MB

  kWb<<<512,256,0,stream>>>(gpw,ipw,opw,piw,fw,gpwb,ipwb,opwb,piwb,fwb);
  kWc<<<256,256,0,stream>>>(dtw,xpw,Wcb);
  k1m<<<dim3(64,8,8),256,0,stream>>>(FT1,FT2,gpwb,g1g,g1b,g1m,g1v,x1b);
  k2<<<16384,256,0,stream>>>(x1b,gcw,g2g,g2b,g2m,g2v,x2b);
  k3<<<8192,256,0,stream>>>(x1b,x2b,sr);
  k4<<<8,256,0,stream>>>(sr,sw1,sw2,sse);
  kWse<<<4096,256,0,stream>>>(prw,sse,Wsb);
  k5m<<<dim3(64,2,8),256,0,stream>>>(x1b,x2b,Wsb,b3g,b3b,b3m,b3v,Fpb,FpTb);
  k6am<<<dim3(64,8,32),256,0,stream>>>(Fpb,FpTb,ipwb,xsT,zT);
  k6b<<<2048,256,0,stream>>>(xsT,c1w,c1b,uT);
  k6cm<<<dim3(64,4,32),256,0,stream>>>(uT,Wcb,dtb,dtT);
  k6bc<<<32768,256,0,stream>>>(uT,xpw,Bc,Cc);
  k7p1<<<256,256,0,stream>>>(uT,dtT,Bc,Alog,Pq);
  k7mid<<<32,256,0,stream>>>(Pq,h0);
  k7p2<<<256,256,0,stream>>>(uT,dtT,zT,Bc,Cc,Alog,Dp,h0);
  k8am<<<dim3(64,2,32),256,0,stream>>>(uT,opwb,Y4);
  k8bm<<<dim3(64,2,8),256,0,stream>>>(Fpb,FpTb,Y4,piwb,pib,ysb);
  k9m<<<dim3(64,2,8),256,0,stream>>>(ysb,Fpb,fwb,(float*)d_out);
}